// Round 14
// baseline (2153.579 us; speedup 1.0000x reference)
//
#include <hip/hip_runtime.h>
#include <hip/hip_bf16.h>

// Problem constants
#define B_  64
#define T_  256
#define D_  384
#define H_  6
#define HD_ 64
#define L_  6
#define V_  65
#define BT  (B_*T_)     // 16384 tokens

typedef __hip_bfloat16 bf16;
typedef unsigned short u16;
typedef short s16;
typedef __attribute__((ext_vector_type(8))) short bf16x8;   // 8 bf16 = 4 VGPR
typedef __attribute__((ext_vector_type(4))) float f32x4;

// Per-layer weight buffer element offsets (bf16 elems)
#define OFF_QKV   0            // [mat][h][hd][d], rows n = mat*384+h*64+hd
#define OFF_PROJ  442368       // [n][k] 384x384
#define OFF_W1T   589824       // [n][k] 1536x384
#define OFF_W2T   1179648      // [n][k] 384x1536
#define OFF_BPROJ 1769472
#define OFF_B1    1769856
#define OFF_B2    1771392
#define OFF_LN1G  1771776
#define OFF_LN1B  1772160
#define OFF_LN2G  1772544
#define OFF_LN2B  1772928
#define WBUF_E    1773312
// Head buffer
#define HOFF_WHT  0            // [n][k] 65x384
#define HOFF_BH   24960
#define HOFF_LNFG 25088
#define HOFF_LNFB 25472
#define HBUF_E    25856

__device__ __forceinline__ float u2f(u16 u) {
  union { unsigned i; float f; } c; c.i = ((unsigned)u) << 16; return c.f;
}
__device__ __forceinline__ bf16 f2b(float x) { return __float2bfloat16(x); }
__device__ __forceinline__ float b2f(bf16 x) { return __bfloat162float(x); }
__device__ __forceinline__ u16 f2u(float x) { bf16 h = f2b(x); return *(u16*)&h; }

__device__ __forceinline__ float pload(const void* p, size_t i, bool f32w) {
  return f32w ? ((const float*)p)[i] : u2f(((const u16*)p)[i]);
}

// ---------------------------------------------------------------------------
// Parallel per-tensor dtype detect (R8-proven). flags[j]=1 => f32 storage.
// flags[20]=1 => idx int64.
// ---------------------------------------------------------------------------
__global__ __launch_bounds__(256) void detect_kernel(
    const void* p1,  const void* p2,  const void* p3,  const void* p4,
    const void* p5,  const void* p6,  const void* p7,  const void* p8,
    const void* p9,  const void* p10, const void* p11, const void* p12,
    const void* p13, const void* p14, const void* p15, const void* p16,
    const void* p17, const void* p18, const void* p19,
    const int* __restrict__ idx, unsigned* flags)
{
  const void* ps[20] = {nullptr, p1, p2, p3, p4, p5, p6, p7, p8, p9, p10,
                        p11, p12, p13, p14, p15, p16, p17, p18, p19};
  const int esz[20] = {16384, 24960, 98304, 884736, 884736, 884736, 884736,
                       2304, 3538944, 9216, 3538944, 2304, 2304, 2304, 2304,
                       2304, 384, 384, 24960, 65};
  __shared__ int r1[256], r2[256];
  int bid = blockIdx.x, tid = threadIdx.x;
  if (bid == 19) {
    int z = 0;
    for (int m = tid; m < 4096; m += 256) z += (idx[2 * m + 1] == 0) ? 1 : 0;
    r1[tid] = z; __syncthreads();
    for (int s = 128; s > 0; s >>= 1) {
      if (tid < s) r1[tid] += r1[tid + s];
      __syncthreads();
    }
    if (tid == 0) flags[20] = (r1[0] >= 4000) ? 1u : 0u;
    return;
  }
  int j = bid + 1;
  const u16* p = (const u16*)ps[j];
  int ns = esz[j] / 2; if (ns > 1024) ns = 1024;
  int band = 0, nz = 0;
  for (int i = tid; i < ns; i += 256) {
    u16 lo = p[2 * i], hi = p[2 * i + 1];
    int e = (lo >> 7) & 0xFF;
    band += (e >= 100 && e <= 127) ? 1 : 0;
    nz   += (lo | hi) ? 1 : 0;
  }
  r1[tid] = band; r2[tid] = nz; __syncthreads();
  for (int s = 128; s > 0; s >>= 1) {
    if (tid < s) { r1[tid] += r1[tid + s]; r2[tid] += r2[tid + s]; }
    __syncthreads();
  }
  if (tid == 0) flags[j] = (r2[0] > 0 && r1[0] * 2 < ns) ? 1u : 0u;
}

__global__ void const_kernel(float* out, int n, float val) {
  int i = blockIdx.x * 256 + threadIdx.x;
  if (i < n) out[i] = val;
}

// ---------------------------------------------------------------------------
// Per-layer weight convert+transpose to bf16.
// ---------------------------------------------------------------------------
__global__ __launch_bounds__(256) void conv_layer(
    const void* Wq, const void* Wk, const void* Wv, const void* Wproj,
    const void* bproj, const void* W1, const void* b1, const void* W2,
    const void* b2, const void* ln1g, const void* ln1b, const void* ln2g,
    const void* ln2b, const unsigned* __restrict__ flags,
    bf16* __restrict__ dst, int l)
{
  int e = blockIdx.x * 256 + threadIdx.x;
  if (e >= WBUF_E) return;
  float v;
  if (e < OFF_PROJ) {                       // QKV^T per head
    int math = e / 24576;
    int rem  = e - math * 24576;
    int hd = rem / 384, d = rem - hd * 384;
    int mat = math / 6, hh = math - mat * 6;
    const void* src = (mat == 0 ? Wq : mat == 1 ? Wk : Wv);
    v = pload(src, ((size_t)(l * 6 + hh) * 384 + d) * 64 + hd, flags[3 + mat] != 0);
  } else if (e < OFF_W1T) {                 // Wproj^T
    int e2 = e - OFF_PROJ;
    int n = e2 / 384, d = e2 - n * 384;
    v = pload(Wproj, ((size_t)l * 384 + d) * 384 + n, flags[6] != 0);
  } else if (e < OFF_W2T) {                 // W1^T
    int e2 = e - OFF_W1T;
    int n = e2 / 384, d = e2 - n * 384;
    v = pload(W1, ((size_t)l * 384 + d) * 1536 + n, flags[8] != 0);
  } else if (e < OFF_BPROJ) {               // W2^T
    int e2 = e - OFF_W2T;
    int n = e2 / 1536, k = e2 - n * 1536;
    v = pload(W2, ((size_t)l * 1536 + k) * 384 + n, flags[10] != 0);
  } else {
    int e2 = e - OFF_BPROJ;
    if      (e2 < 384)  v = pload(bproj, (size_t)l * 384 + e2, flags[7] != 0);
    else if (e2 < 1920) v = pload(b1, (size_t)l * 1536 + (e2 - 384), flags[9] != 0);
    else if (e2 < 2304) v = pload(b2, (size_t)l * 384 + (e2 - 1920), flags[11] != 0);
    else if (e2 < 2688) v = pload(ln1g, (size_t)l * 384 + (e2 - 2304), flags[12] != 0);
    else if (e2 < 3072) v = pload(ln1b, (size_t)l * 384 + (e2 - 2688), flags[13] != 0);
    else if (e2 < 3456) v = pload(ln2g, (size_t)l * 384 + (e2 - 3072), flags[14] != 0);
    else                v = pload(ln2b, (size_t)l * 384 + (e2 - 3456), flags[15] != 0);
  }
  dst[e] = f2b(v);
}

__global__ __launch_bounds__(256) void conv_head(
    const void* Wh, const void* bh, const void* lnfg, const void* lnfb,
    const unsigned* __restrict__ flags, bf16* __restrict__ dst)
{
  int e = blockIdx.x * 256 + threadIdx.x;
  if (e >= HBUF_E) return;
  float v = 0.f;
  if (e < HOFF_BH) {                        // Whead^T [65][384]
    int n = e / 384, d = e - n * 384;
    v = pload(Wh, (size_t)d * 65 + n, flags[18] != 0);
  } else if (e < 25025) {
    v = pload(bh, e - HOFF_BH, flags[19] != 0);
  } else if (e < HOFF_LNFG) {
    v = 0.f;
  } else if (e < HOFF_LNFB) {
    v = pload(lnfg, e - HOFF_LNFG, flags[16] != 0);
  } else {
    v = pload(lnfb, e - HOFF_LNFB, flags[17] != 0);
  }
  dst[e] = f2b(v);
}

// ---------------------------------------------------------------------------
__global__ __launch_bounds__(256) void embed_kernel(
    const void* __restrict__ idx, const void* __restrict__ tok,
    const void* __restrict__ pos, bf16* __restrict__ x,
    const unsigned* __restrict__ flags)
{
  int i   = blockIdx.x * 256 + threadIdx.x;   // < BT*D_
  int tkn = i / D_;
  int d   = i - tkn * D_;
  int t   = tkn & (T_ - 1);
  long long tix;
  if (flags[20]) tix = ((const long long*)idx)[tkn];
  else           tix = ((const int*)idx)[tkn];
  float v = pload(tok, (size_t)tix * D_ + d, flags[1] != 0)
          + pload(pos, (size_t)t * D_ + d, flags[2] != 0);
  x[i] = f2b(v);
}

// ---------------------------------------------------------------------------
// Per-token LN stats: mean, rsqrt(var+eps). One wave per token.
// ---------------------------------------------------------------------------
__global__ __launch_bounds__(256) void stats_kernel(
    const bf16* __restrict__ x, float2* __restrict__ st)
{
  int w = threadIdx.x >> 6, lane = threadIdx.x & 63;
  int tok = blockIdx.x * 4 + w;
  const bf16* xr = x + (size_t)tok * D_;
  float v[6]; float s = 0.f;
#pragma unroll
  for (int j = 0; j < 6; j++) { v[j] = b2f(xr[lane + 64 * j]); s += v[j]; }
#pragma unroll
  for (int o = 1; o < 64; o <<= 1) s += __shfl_xor(s, o, 64);
  float mean = s * (1.0f / D_);
  float sq = 0.f;
#pragma unroll
  for (int j = 0; j < 6; j++) { float d0 = v[j] - mean; sq += d0 * d0; }
#pragma unroll
  for (int o = 1; o < 64; o <<= 1) sq += __shfl_xor(sq, o, 64);
  if (lane == 0) {
    float inv = 1.0f / sqrtf(sq * (1.0f / D_) + 1e-3f);
    st[tok] = make_float2(mean, inv);
  }
}

// ---------------------------------------------------------------------------
// mg128: MFMA GEMM core, tile 128m x 128n x 64k (m97-style ratio).
// 4 waves, each owns a 64x64 quadrant (4x4 16x16 frags, 64 acc VGPRs).
// W pre-transposed [N][K] bf16. AMODE: LN fused into A staging.
// Epilogue via lambda epi(m_tile_local, n_global, val).
// Fragment maps identical to R9/R10-verified core.
// ---------------------------------------------------------------------------
template<int AMODE, class Epi>
__device__ __forceinline__ void mg128(
    s16* __restrict__ Xs, s16* __restrict__ Ws,
    const u16* __restrict__ A, const float2* __restrict__ st,
    const u16* __restrict__ lng, const u16* __restrict__ lnb,
    const u16* __restrict__ WT, int N, int K, int arow0, int n0, Epi epi)
{
  int tid = threadIdx.x;
  int w = tid >> 6, lane = tid & 63;
  int quad = lane >> 4, l15 = lane & 15;
  int wm = (w >> 1) * 64, wn = (w & 1) * 64;
  f32x4 acc[4][4];
#pragma unroll
  for (int i = 0; i < 4; i++)
#pragma unroll
    for (int j = 0; j < 4; j++) acc[i][j] = (f32x4){0.f, 0.f, 0.f, 0.f};

  int sr = tid >> 1, sc = (tid & 1) * 32;   // staging: 128 rows x 32 k halves
  float mean = 0.f, inv = 1.f;
  if (AMODE) { float2 s2 = st[arow0 + sr]; mean = s2.x; inv = s2.y; }
  const u16* Ap0 = A + (size_t)(arow0 + sr) * K + sc;
  bool nv = (n0 + sr) < N;
  const u16* Wp0 = WT + (size_t)(nv ? (n0 + sr) : 0) * K + sc;

  for (int k0 = 0; k0 < K; k0 += 64) {
    bf16x8 xv[4], wv[4];
#pragma unroll
    for (int i = 0; i < 4; i++) xv[i] = *(const bf16x8*)(Ap0 + k0 + 8 * i);
    if (AMODE) {
#pragma unroll
      for (int i = 0; i < 4; i++) {
        bf16x8 g = *(const bf16x8*)(lng + sc + k0 + 8 * i);
        bf16x8 b = *(const bf16x8*)(lnb + sc + k0 + 8 * i);
#pragma unroll
        for (int j = 0; j < 8; j++) {
          float f = (u2f((u16)xv[i][j]) - mean) * inv * u2f((u16)g[j])
                  + u2f((u16)b[j]);
          xv[i][j] = (s16)f2u(f);
        }
      }
    }
#pragma unroll
    for (int i = 0; i < 4; i++)
      wv[i] = nv ? *(const bf16x8*)(Wp0 + k0 + 8 * i)
                 : (bf16x8){0,0,0,0,0,0,0,0};
    __syncthreads();
#pragma unroll
    for (int i = 0; i < 4; i++) {
      *(bf16x8*)&Xs[sr * 72 + sc + 8 * i] = xv[i];
      *(bf16x8*)&Ws[sr * 72 + sc + 8 * i] = wv[i];
    }
    __syncthreads();
#pragma unroll
    for (int kh = 0; kh < 2; kh++) {
      int kk = kh * 32 + quad * 8;
      bf16x8 am[4], bn[4];
#pragma unroll
      for (int i = 0; i < 4; i++)
        am[i] = *(const bf16x8*)&Xs[(wm + i * 16 + l15) * 72 + kk];
#pragma unroll
      for (int j = 0; j < 4; j++)
        bn[j] = *(const bf16x8*)&Ws[(wn + j * 16 + l15) * 72 + kk];
#pragma unroll
      for (int i = 0; i < 4; i++)
#pragma unroll
        for (int j = 0; j < 4; j++)
          acc[i][j] = __builtin_amdgcn_mfma_f32_16x16x32_bf16(am[i], bn[j], acc[i][j], 0, 0, 0);
    }
  }

  // epilogue: C frag row=quad*4+r, col=l15
#pragma unroll
  for (int i = 0; i < 4; i++)
#pragma unroll
    for (int j = 0; j < 4; j++)
#pragma unroll
      for (int r = 0; r < 4; r++) {
        int m = wm + i * 16 + quad * 4 + r;       // tile-local
        int n = n0 + wn + j * 16 + l15;           // global col
        if (n < N) epi(m, n, acc[i][j][r]);
      }
}

#define MG128_LDS __shared__ s16 Xs[128 * 72]; __shared__ s16 Ws[128 * 72];

// QKV as ONE GEMM: N=1152 (rows of Wbuf = mat*384+h*64+hd). LN1-fused.
// grid (9, MCa/128). Scatter epilogue into chunk layout [mat][h][lm][hd].
__global__ __launch_bounds__(256) void qkv128(
    const bf16* x, const float2* st, const bf16* Wbuf, bf16* qkvc,
    int MCa, int tok0)
{
  MG128_LDS
  int n0 = blockIdx.x * 128, mloc0 = blockIdx.y * 128;
  auto epi = [&](int m, int n, float v) {
    int mat = n / 384;
    int rem = n - mat * 384;
    int hh = rem >> 6, hd = rem & 63;
    qkvc[(size_t)mat * MCa * D_ + (size_t)hh * MCa * HD_
         + (size_t)(mloc0 + m) * HD_ + hd] = f2b(v);
  };
  mg128<1>(Xs, Ws, (const u16*)x, st,
           (const u16*)Wbuf + OFF_LN1G, (const u16*)Wbuf + OFF_LN1B,
           (const u16*)Wbuf + OFF_QKV, 1152, D_, tok0 + mloc0, n0, epi);
}

// proj: +bias +resid, writes x. grid (3, M/128). arow0/crow0 may differ.
__global__ __launch_bounds__(256) void proj128(
    const bf16* A, const bf16* Wbuf, bf16* x, int arow0_, int crow0_)
{
  MG128_LDS
  int n0 = blockIdx.x * 128, m0 = blockIdx.y * 128;
  const bf16* bias = (const bf16*)Wbuf + OFF_BPROJ;
  int crow0 = crow0_ + m0;
  auto epi = [&](int m, int n, float v) {
    size_t a = (size_t)(crow0 + m) * D_ + n;
    x[a] = f2b(v + b2f(bias[n]) + b2f(x[a]));
  };
  mg128<0>(Xs, Ws, (const u16*)A, nullptr, nullptr, nullptr,
           (const u16*)Wbuf + OFF_PROJ, D_, D_, arow0_ + m0, n0, epi);
}

// ffn1: LN2-fused, ReLU, +bias -> midc (chunk-local). grid (12, MCf/128).
__global__ __launch_bounds__(256) void ffn1_128(
    const bf16* x, const float2* st, const bf16* Wbuf, bf16* midc, int tok0)
{
  MG128_LDS
  int n0 = blockIdx.x * 128, m0 = blockIdx.y * 128;
  const bf16* bias = (const bf16*)Wbuf + OFF_B1;
  auto epi = [&](int m, int n, float v) {
    float r = v + b2f(bias[n]);
    midc[(size_t)(m0 + m) * (4 * D_) + n] = f2b(fmaxf(r, 0.f));
  };
  mg128<1>(Xs, Ws, (const u16*)x, st,
           (const u16*)Wbuf + OFF_LN2G, (const u16*)Wbuf + OFF_LN2B,
           (const u16*)Wbuf + OFF_W1T, 4 * D_, D_, tok0 + m0, n0, epi);
}

// ffn2: +bias +resid -> x. grid (3, MCf/128). K=1536.
__global__ __launch_bounds__(256) void ffn2_128(
    const bf16* midc, const bf16* Wbuf, bf16* x, int tok0)
{
  MG128_LDS
  int n0 = blockIdx.x * 128, m0 = blockIdx.y * 128;
  const bf16* bias = (const bf16*)Wbuf + OFF_B2;
  int crow0 = tok0 + m0;
  auto epi = [&](int m, int n, float v) {
    size_t a = (size_t)(crow0 + m) * D_ + n;
    x[a] = f2b(v + b2f(bias[n]) + b2f(x[a]));
  };
  mg128<0>(Xs, Ws, (const u16*)midc, nullptr, nullptr, nullptr,
           (const u16*)Wbuf + OFF_W2T, D_, 4 * D_, m0, n0, epi);
}

// ---------------------------------------------------------------------------
// Old 64-wide MFMA core kept for the head (N=65).
// ---------------------------------------------------------------------------
#define XS_S 72
#define WT_S 72
__global__ __launch_bounds__(256) void head_mfma(
    const bf16* x, const float2* st, const bf16* Hbuf, float* out)
{
  __shared__ s16 Xs[128 * XS_S]; __shared__ s16 Wt[64 * WT_S];
  const u16* lng = (const u16*)Hbuf + HOFF_LNFG;
  const u16* lnb = (const u16*)Hbuf + HOFF_LNFB;
  const u16* WT  = (const u16*)Hbuf + HOFF_WHT;
  const bf16* bias = (const bf16*)Hbuf + HOFF_BH;
  int n0 = blockIdx.x * 64, m0 = blockIdx.y * 128;
  int N = V_, K = D_;
  int tid = threadIdx.x;
  int w = tid >> 6, lane = tid & 63;
  int quad = lane >> 4, l15 = lane & 15;
  f32x4 acc[2][4];
#pragma unroll
  for (int i = 0; i < 2; i++)
#pragma unroll
    for (int j = 0; j < 4; j++) acc[i][j] = (f32x4){0.f, 0.f, 0.f, 0.f};
  int xr = tid >> 1, xc = (tid & 1) * 32;
  int wn = tid >> 2, wk = (tid & 3) * 16;
  float2 s2 = st[m0 + xr];
  float mean = s2.x, inv = s2.y;
  const u16* Ap0 = (const u16*)x + (size_t)(m0 + xr) * K + xc;
  bool wvalid = (n0 + wn) < N;
  const u16* Wp0 = WT + (size_t)(wvalid ? (n0 + wn) : 0) * K + wk;
  for (int k0 = 0; k0 < K; k0 += 64) {
    bf16x8 xv[4];
#pragma unroll
    for (int i = 0; i < 4; i++) xv[i] = *(const bf16x8*)(Ap0 + k0 + 8 * i);
#pragma unroll
    for (int i = 0; i < 4; i++) {
      bf16x8 g = *(const bf16x8*)(lng + xc + k0 + 8 * i);
      bf16x8 b = *(const bf16x8*)(lnb + xc + k0 + 8 * i);
#pragma unroll
      for (int j = 0; j < 8; j++) {
        float f = (u2f((u16)xv[i][j]) - mean) * inv * u2f((u16)g[j])
                + u2f((u16)b[j]);
        xv[i][j] = (s16)f2u(f);
      }
    }
    bf16x8 wv[2];
#pragma unroll
    for (int i = 0; i < 2; i++)
      wv[i] = wvalid ? *(const bf16x8*)(Wp0 + k0 + 8 * i)
                     : (bf16x8){0,0,0,0,0,0,0,0};
    __syncthreads();
#pragma unroll
    for (int i = 0; i < 4; i++)
      *(bf16x8*)&Xs[xr * XS_S + xc + 8 * i] = xv[i];
#pragma unroll
    for (int i = 0; i < 2; i++)
      *(bf16x8*)&Wt[wn * WT_S + wk + 8 * i] = wv[i];
    __syncthreads();
#pragma unroll
    for (int kh = 0; kh < 2; kh++) {
      int kk = kh * 32 + quad * 8;
      bf16x8 a0 = *(const bf16x8*)&Xs[(w * 32 + l15) * XS_S + kk];
      bf16x8 a1 = *(const bf16x8*)&Xs[(w * 32 + 16 + l15) * XS_S + kk];
#pragma unroll
      for (int nt = 0; nt < 4; nt++) {
        bf16x8 b = *(const bf16x8*)&Wt[(nt * 16 + l15) * WT_S + kk];
        acc[0][nt] = __builtin_amdgcn_mfma_f32_16x16x32_bf16(a0, b, acc[0][nt], 0, 0, 0);
        acc[1][nt] = __builtin_amdgcn_mfma_f32_16x16x32_bf16(a1, b, acc[1][nt], 0, 0, 0);
      }
    }
  }
#pragma unroll
  for (int sub = 0; sub < 2; sub++)
#pragma unroll
    for (int nt = 0; nt < 4; nt++)
#pragma unroll
      for (int r = 0; r < 4; r++) {
        int m = w * 32 + sub * 16 + quad * 4 + r;
        int n = n0 + nt * 16 + l15;
        if (n < N)
          out[(size_t)(m0 + m) * V_ + n] = acc[sub][nt][r] + b2f(bias[n]);
      }
}

// ---------------------------------------------------------------------------
// MFMA flash attention with ONLINE softmax (R13-proven).
// ---------------------------------------------------------------------------
__global__ __launch_bounds__(256) void attn4_kernel(
    const bf16* __restrict__ Q, const bf16* __restrict__ K,
    const bf16* __restrict__ V, bf16* __restrict__ att, int MCa, int row0)
{
  __shared__ s16 Qs[64 * 72];
  __shared__ s16 Ks[64 * 72];
  __shared__ s16 Vs[64 * 73];
  __shared__ s16 Ps[4][16 * 72];
  const float scale = 0.05103103630798288f;   // 384^-0.5 (full-D scaling!)
  int tid = threadIdx.x;
  int w = tid >> 6, lane = tid & 63;
  int quad = lane >> 4, l15 = lane & 15;
  int bid = blockIdx.x;
  int qt = bid & 3;
  int bh = bid >> 2;
  int b = bh / H_, h = bh - b * H_;
  size_t base = ((size_t)h * MCa + (size_t)b * T_) * HD_;
  int q0 = qt * 64;
  int cq = qt;

#pragma unroll
  for (int i = 0; i < 2; i++) {
    int e = i * 256 + tid;
    int r = e >> 3, c = (e & 7) * 8;
    *(bf16x8*)&Qs[r * 72 + c] =
        *(const bf16x8*)((const u16*)Q + base + (size_t)(q0 + r) * HD_ + c);
  }

  float mrow[4] = {-1e30f, -1e30f, -1e30f, -1e30f};
  float lrow[4] = {0.f, 0.f, 0.f, 0.f};
  f32x4 O[4];
#pragma unroll
  for (int nt = 0; nt < 4; nt++) O[nt] = (f32x4){0.f, 0.f, 0.f, 0.f};

  for (int c = 0; c <= cq; c++) {
    __syncthreads();
#pragma unroll
    for (int i = 0; i < 2; i++) {
      int e = i * 256 + tid;
      int r = e >> 3, cc = (e & 7) * 8;
      *(bf16x8*)&Ks[r * 72 + cc] =
          *(const bf16x8*)((const u16*)K + base + (size_t)(c * 64 + r) * HD_ + cc);
      bf16x8 vv =
          *(const bf16x8*)((const u16*)V + base + (size_t)(c * 64 + r) * HD_ + cc);
#pragma unroll
      for (int k = 0; k < 8; k++) Vs[r * 73 + cc + k] = vv[k];
    }
    __syncthreads();

    f32x4 S[4];
#pragma unroll
    for (int nt = 0; nt < 4; nt++) S[nt] = (f32x4){0.f, 0.f, 0.f, 0.f};
#pragma unroll
    for (int ks = 0; ks < 2; ks++) {
      int kk = ks * 32 + quad * 8;
      bf16x8 a = *(const bf16x8*)&Qs[(w * 16 + l15) * 72 + kk];
#pragma unroll
      for (int nt = 0; nt < 4; nt++) {
        bf16x8 bb8 = *(const bf16x8*)&Ks[(nt * 16 + l15) * 72 + kk];
        S[nt] = __builtin_amdgcn_mfma_f32_16x16x32_bf16(a, bb8, S[nt], 0, 0, 0);
      }
    }

#pragma unroll
    for (int nt = 0; nt < 4; nt++)
#pragma unroll
      for (int r = 0; r < 4; r++) {
        int qrow = q0 + w * 16 + quad * 4 + r;
        int sg = c * 64 + nt * 16 + l15;
        float v = S[nt][r] * scale;
        S[nt][r] = (sg <= qrow) ? v : -1e30f;
      }

    float alpha[4];
#pragma unroll
    for (int r = 0; r < 4; r++) {
      float mc = fmaxf(fmaxf(S[0][r], S[1][r]), fmaxf(S[2][r], S[3][r]));
#pragma unroll
      for (int o = 1; o < 16; o <<= 1) mc = fmaxf(mc, __shfl_xor(mc, o, 64));
      float mn = fmaxf(mrow[r], mc);
      alpha[r] = __expf(mrow[r] - mn);
      mrow[r] = mn;
      float s = 0.f;
#pragma unroll
      for (int nt = 0; nt < 4; nt++) {
        float p = __expf(S[nt][r] - mn);
        S[nt][r] = p;
        s += p;
      }
#pragma unroll
      for (int o = 1; o < 16; o <<= 1) s += __shfl_xor(s, o, 64);
      lrow[r] = lrow[r] * alpha[r] + s;
    }
#pragma unroll
    for (int nt = 0; nt < 4; nt++)
#pragma unroll
      for (int r = 0; r < 4; r++) O[nt][r] *= alpha[r];

#pragma unroll
    for (int nt = 0; nt < 4; nt++)
#pragma unroll
      for (int r = 0; r < 4; r++)
        Ps[w][(quad * 4 + r) * 72 + nt * 16 + l15] = (s16)f2u(S[nt][r]);
    __syncthreads();
#pragma unroll
    for (int ks = 0; ks < 2; ks++) {
      bf16x8 a = *(const bf16x8*)&Ps[w][l15 * 72 + ks * 32 + quad * 8];
#pragma unroll
      for (int nt = 0; nt < 4; nt++) {
        bf16x8 bb8;
#pragma unroll
        for (int j = 0; j < 8; j++)
          bb8[j] = Vs[(ks * 32 + quad * 8 + j) * 73 + nt * 16 + l15];
        O[nt] = __builtin_amdgcn_mfma_f32_16x16x32_bf16(a, bb8, O[nt], 0, 0, 0);
      }
    }
  }

#pragma unroll
  for (int r = 0; r < 4; r++) {
    float invl = 1.0f / lrow[r];
#pragma unroll
    for (int nt = 0; nt < 4; nt++) {
      int qrow = q0 + w * 16 + quad * 4 + r;
      att[(size_t)(row0 + b * T_ + qrow) * D_ + h * HD_ + nt * 16 + l15] =
          f2b(O[nt][r] * invl);
    }
  }
}

// ---------------------------------------------------------------------------
extern "C" void kernel_launch(void* const* d_in, const int* in_sizes, int n_in,
                              void* d_out, int out_size, void* d_ws, size_t ws_size,
                              hipStream_t stream)
{
  float* out = (float*)d_out;
  dim3 blk(256);
  int outg = (out_size + 255) / 256;

  static const int expected[20] = {
      16384, 24960, 98304, 884736, 884736, 884736, 884736, 2304,
      3538944, 9216, 3538944, 2304, 2304, 2304, 2304, 2304, 384, 384,
      24960, 65};
  if (n_in != 20) { const_kernel<<<outg, blk, 0, stream>>>(out, out_size, 5.0f); return; }
  for (int i = 0; i < 20; i++)
    if (in_sizes[i] != expected[i]) {
      const_kernel<<<outg, blk, 0, stream>>>(out, out_size, 10.0f * (i + 1));
      return;
    }
  if (out_size != BT * V_) { const_kernel<<<outg, blk, 0, stream>>>(out, out_size, 7.0f); return; }

  const void* idx   = d_in[0];
  const void* tok   = d_in[1];
  const void* pos   = d_in[2];
  const void* Wq    = d_in[3];
  const void* Wk    = d_in[4];
  const void* Wv    = d_in[5];
  const void* Wproj = d_in[6];
  const void* bproj = d_in[7];
  const void* W1    = d_in[8];
  const void* b1    = d_in[9];
  const void* W2    = d_in[10];
  const void* b2    = d_in[11];
  const void* ln1g  = d_in[12];
  const void* ln1b  = d_in[13];
  const void* ln2g  = d_in[14];
  const void* ln2b  = d_in[15];
  const void* lnfg  = d_in[16];
  const void* lnfb  = d_in[17];
  const void* Whead = d_in[18];
  const void* bhead = d_in[19];

  const size_t off_x  = 256;
  const size_t off_st = off_x + (size_t)BT * D_ * 2;
  const size_t off_wb = off_st + (size_t)BT * 8;
  const size_t off_hb = off_wb + (size_t)WBUF_E * 2;
  const size_t fixed  = off_hb + ((size_t)HBUF_E * 2 + 63) / 64 * 64;
  if (ws_size < fixed + (size_t)BT * D_ * 2 / 4) {
    const_kernel<<<outg, blk, 0, stream>>>(out, out_size, 0.0f);
    return;
  }
  size_t region = ws_size - fixed;

  int na = 0, fullAtt = 0;
  const int cands[6] = {4, 8, 16, 32, 64, 0};
  for (int i = 0; cands[i]; i++) {
    size_t need = ((size_t)3 * (BT / cands[i]) + BT) * D_ * 2;
    if (need <= region) { na = cands[i]; fullAtt = 1; break; }
  }
  if (!na) {
    for (int i = 0; cands[i]; i++) {
      size_t need = (size_t)4 * (BT / cands[i]) * D_ * 2;
      if (need <= region) { na = cands[i]; break; }
    }
  }
  if (!na) { const_kernel<<<outg, blk, 0, stream>>>(out, out_size, 0.0f); return; }
  int nf = 0;
  const int candf[7] = {2, 4, 8, 16, 32, 64, 0};
  for (int i = 0; candf[i]; i++) {
    if ((size_t)4 * (BT / candf[i]) * D_ * 2 <= region) { nf = candf[i]; break; }
  }
  const int MCa = BT / na, MCf = BT / nf;
  const int CBa = MCa / T_;

  char* wsb = (char*)d_ws;
  unsigned* flags = (unsigned*)wsb;
  bf16*   x    = (bf16*)(wsb + off_x);
  float2* st   = (float2*)(wsb + off_st);
  bf16*   Wbuf = (bf16*)(wsb + off_wb);
  bf16*   Hbuf = (bf16*)(wsb + off_hb);
  bf16*   qkvc = (bf16*)(wsb + fixed);
  bf16*   att  = qkvc + (size_t)3 * MCa * D_;
  bf16*   midc = qkvc;

  detect_kernel<<<dim3(20), blk, 0, stream>>>(
      tok, pos, Wq, Wk, Wv, Wproj, bproj, W1, b1, W2, b2,
      ln1g, ln1b, ln2g, ln2b, lnfg, lnfb, Whead, bhead,
      (const int*)idx, flags);
  embed_kernel<<<dim3(BT * D_ / 256), blk, 0, stream>>>(idx, tok, pos, x, flags);
  conv_head<<<dim3((HBUF_E + 255) / 256), blk, 0, stream>>>(
      Whead, bhead, lnfg, lnfb, flags, Hbuf);

  for (int l = 0; l < L_; l++) {
    conv_layer<<<dim3((WBUF_E + 255) / 256), blk, 0, stream>>>(
        Wq, Wk, Wv, Wproj, bproj, W1, b1, W2, b2,
        ln1g, ln1b, ln2g, ln2b, flags, Wbuf, l);
    stats_kernel<<<dim3(BT / 4), blk, 0, stream>>>(x, st);
    if (fullAtt) {
      for (int c = 0; c < na; c++) {
        int tok0 = c * MCa;
        qkv128<<<dim3(9, MCa / 128), blk, 0, stream>>>(x, st, Wbuf, qkvc, MCa, tok0);
        attn4_kernel<<<dim3(CBa * H_ * 4), blk, 0, stream>>>(
            qkvc, qkvc + (size_t)MCa * D_, qkvc + (size_t)2 * MCa * D_, att, MCa, tok0);
      }
      proj128<<<dim3(3, BT / 128), blk, 0, stream>>>(att, Wbuf, x, 0, 0);
    } else {
      for (int c = 0; c < na; c++) {
        int tok0 = c * MCa;
        qkv128<<<dim3(9, MCa / 128), blk, 0, stream>>>(x, st, Wbuf, qkvc, MCa, tok0);
        attn4_kernel<<<dim3(CBa * H_ * 4), blk, 0, stream>>>(
            qkvc, qkvc + (size_t)MCa * D_, qkvc + (size_t)2 * MCa * D_, att, MCa, 0);
        proj128<<<dim3(3, MCa / 128), blk, 0, stream>>>(att, Wbuf, x, 0, tok0);
      }
    }
    stats_kernel<<<dim3(BT / 4), blk, 0, stream>>>(x, st);
    for (int f = 0; f < nf; f++) {
      int tok0 = f * MCf;
      ffn1_128<<<dim3(12, MCf / 128), blk, 0, stream>>>(x, st, Wbuf, midc, tok0);
      ffn2_128<<<dim3(3, MCf / 128), blk, 0, stream>>>(midc, Wbuf, x, tok0);
    }
  }

  stats_kernel<<<dim3(BT / 4), blk, 0, stream>>>(x, st);
  head_mfma<<<dim3(2, BT / 128), blk, 0, stream>>>(x, st, Hbuf, out);
}

// Round 15
// 1516.794 us; speedup vs baseline: 1.4198x; 1.4198x over previous
//
#include <hip/hip_runtime.h>
#include <hip/hip_bf16.h>

// Problem constants
#define B_  64
#define T_  256
#define D_  384
#define H_  6
#define HD_ 64
#define L_  6
#define V_  65
#define BT  (B_*T_)     // 16384 tokens

typedef __hip_bfloat16 bf16;
typedef unsigned short u16;
typedef short s16;
typedef __attribute__((ext_vector_type(8))) short bf16x8;   // 8 bf16 = 4 VGPR
typedef __attribute__((ext_vector_type(4))) float f32x4;

// Per-layer weight buffer element offsets (bf16 elems)
#define OFF_QKV   0            // rows n = mat*384+h*64+hd, [n][k] 1152x384
#define OFF_PROJ  442368       // [n][k] 384x384
#define OFF_W1T   589824       // [n][k] 1536x384
#define OFF_W2T   1179648      // [n][k] 384x1536
#define OFF_BPROJ 1769472
#define OFF_B1    1769856
#define OFF_B2    1771392
#define OFF_LN1G  1771776
#define OFF_LN1B  1772160
#define OFF_LN2G  1772544
#define OFF_LN2B  1772928
#define WBUF_E    1773312
// Head buffer
#define HOFF_WHT  0            // [n][k] 65x384
#define HOFF_BH   24960
#define HOFF_LNFG 25088
#define HOFF_LNFB 25472
#define HBUF_E    25856

__device__ __forceinline__ float u2f(u16 u) {
  union { unsigned i; float f; } c; c.i = ((unsigned)u) << 16; return c.f;
}
__device__ __forceinline__ bf16 f2b(float x) { return __float2bfloat16(x); }
__device__ __forceinline__ float b2f(bf16 x) { return __bfloat162float(x); }
__device__ __forceinline__ u16 f2u(float x) { bf16 h = f2b(x); return *(u16*)&h; }

__device__ __forceinline__ float pload(const void* p, size_t i, bool f32w) {
  return f32w ? ((const float*)p)[i] : u2f(((const u16*)p)[i]);
}

// ---------------------------------------------------------------------------
// Parallel per-tensor dtype detect (R8-proven).
// ---------------------------------------------------------------------------
__global__ __launch_bounds__(256) void detect_kernel(
    const void* p1,  const void* p2,  const void* p3,  const void* p4,
    const void* p5,  const void* p6,  const void* p7,  const void* p8,
    const void* p9,  const void* p10, const void* p11, const void* p12,
    const void* p13, const void* p14, const void* p15, const void* p16,
    const void* p17, const void* p18, const void* p19,
    const int* __restrict__ idx, unsigned* flags)
{
  const void* ps[20] = {nullptr, p1, p2, p3, p4, p5, p6, p7, p8, p9, p10,
                        p11, p12, p13, p14, p15, p16, p17, p18, p19};
  const int esz[20] = {16384, 24960, 98304, 884736, 884736, 884736, 884736,
                       2304, 3538944, 9216, 3538944, 2304, 2304, 2304, 2304,
                       2304, 384, 384, 24960, 65};
  __shared__ int r1[256], r2[256];
  int bid = blockIdx.x, tid = threadIdx.x;
  if (bid == 19) {
    int z = 0;
    for (int m = tid; m < 4096; m += 256) z += (idx[2 * m + 1] == 0) ? 1 : 0;
    r1[tid] = z; __syncthreads();
    for (int s = 128; s > 0; s >>= 1) {
      if (tid < s) r1[tid] += r1[tid + s];
      __syncthreads();
    }
    if (tid == 0) flags[20] = (r1[0] >= 4000) ? 1u : 0u;
    return;
  }
  int j = bid + 1;
  const u16* p = (const u16*)ps[j];
  int ns = esz[j] / 2; if (ns > 1024) ns = 1024;
  int band = 0, nz = 0;
  for (int i = tid; i < ns; i += 256) {
    u16 lo = p[2 * i], hi = p[2 * i + 1];
    int e = (lo >> 7) & 0xFF;
    band += (e >= 100 && e <= 127) ? 1 : 0;
    nz   += (lo | hi) ? 1 : 0;
  }
  r1[tid] = band; r2[tid] = nz; __syncthreads();
  for (int s = 128; s > 0; s >>= 1) {
    if (tid < s) { r1[tid] += r1[tid + s]; r2[tid] += r2[tid + s]; }
    __syncthreads();
  }
  if (tid == 0) flags[j] = (r2[0] > 0 && r1[0] * 2 < ns) ? 1u : 0u;
}

__global__ void const_kernel(float* out, int n, float val) {
  int i = blockIdx.x * 256 + threadIdx.x;
  if (i < n) out[i] = val;
}

// ---------------------------------------------------------------------------
// Per-layer weight convert+transpose to bf16.
// ---------------------------------------------------------------------------
__global__ __launch_bounds__(256) void conv_layer(
    const void* Wq, const void* Wk, const void* Wv, const void* Wproj,
    const void* bproj, const void* W1, const void* b1, const void* W2,
    const void* b2, const void* ln1g, const void* ln1b, const void* ln2g,
    const void* ln2b, const unsigned* __restrict__ flags,
    bf16* __restrict__ dst, int l)
{
  int e = blockIdx.x * 256 + threadIdx.x;
  if (e >= WBUF_E) return;
  float v;
  if (e < OFF_PROJ) {                       // QKV^T per head
    int math = e / 24576;
    int rem  = e - math * 24576;
    int hd = rem / 384, d = rem - hd * 384;
    int mat = math / 6, hh = math - mat * 6;
    const void* src = (mat == 0 ? Wq : mat == 1 ? Wk : Wv);
    v = pload(src, ((size_t)(l * 6 + hh) * 384 + d) * 64 + hd, flags[3 + mat] != 0);
  } else if (e < OFF_W1T) {                 // Wproj^T
    int e2 = e - OFF_PROJ;
    int n = e2 / 384, d = e2 - n * 384;
    v = pload(Wproj, ((size_t)l * 384 + d) * 384 + n, flags[6] != 0);
  } else if (e < OFF_W2T) {                 // W1^T
    int e2 = e - OFF_W1T;
    int n = e2 / 384, d = e2 - n * 384;
    v = pload(W1, ((size_t)l * 384 + d) * 1536 + n, flags[8] != 0);
  } else if (e < OFF_BPROJ) {               // W2^T
    int e2 = e - OFF_W2T;
    int n = e2 / 1536, k = e2 - n * 1536;
    v = pload(W2, ((size_t)l * 1536 + k) * 384 + n, flags[10] != 0);
  } else {
    int e2 = e - OFF_BPROJ;
    if      (e2 < 384)  v = pload(bproj, (size_t)l * 384 + e2, flags[7] != 0);
    else if (e2 < 1920) v = pload(b1, (size_t)l * 1536 + (e2 - 384), flags[9] != 0);
    else if (e2 < 2304) v = pload(b2, (size_t)l * 384 + (e2 - 1920), flags[11] != 0);
    else if (e2 < 2688) v = pload(ln1g, (size_t)l * 384 + (e2 - 2304), flags[12] != 0);
    else if (e2 < 3072) v = pload(ln1b, (size_t)l * 384 + (e2 - 2688), flags[13] != 0);
    else if (e2 < 3456) v = pload(ln2g, (size_t)l * 384 + (e2 - 3072), flags[14] != 0);
    else                v = pload(ln2b, (size_t)l * 384 + (e2 - 3456), flags[15] != 0);
  }
  dst[e] = f2b(v);
}

__global__ __launch_bounds__(256) void conv_head(
    const void* Wh, const void* bh, const void* lnfg, const void* lnfb,
    const unsigned* __restrict__ flags, bf16* __restrict__ dst)
{
  int e = blockIdx.x * 256 + threadIdx.x;
  if (e >= HBUF_E) return;
  float v = 0.f;
  if (e < HOFF_BH) {                        // Whead^T [65][384]
    int n = e / 384, d = e - n * 384;
    v = pload(Wh, (size_t)d * 65 + n, flags[18] != 0);
  } else if (e < 25025) {
    v = pload(bh, e - HOFF_BH, flags[19] != 0);
  } else if (e < HOFF_LNFG) {
    v = 0.f;
  } else if (e < HOFF_LNFB) {
    v = pload(lnfg, e - HOFF_LNFG, flags[16] != 0);
  } else {
    v = pload(lnfb, e - HOFF_LNFB, flags[17] != 0);
  }
  dst[e] = f2b(v);
}

// ---------------------------------------------------------------------------
__global__ __launch_bounds__(256) void embed_kernel(
    const void* __restrict__ idx, const void* __restrict__ tok,
    const void* __restrict__ pos, bf16* __restrict__ x,
    const unsigned* __restrict__ flags)
{
  int i   = blockIdx.x * 256 + threadIdx.x;   // < BT*D_
  int tkn = i / D_;
  int d   = i - tkn * D_;
  int t   = tkn & (T_ - 1);
  long long tix;
  if (flags[20]) tix = ((const long long*)idx)[tkn];
  else           tix = ((const int*)idx)[tkn];
  float v = pload(tok, (size_t)tix * D_ + d, flags[1] != 0)
          + pload(pos, (size_t)t * D_ + d, flags[2] != 0);
  x[i] = f2b(v);
}

// ---------------------------------------------------------------------------
// Per-token LN stats: mean, rsqrt(var+eps). One wave per token.
// ---------------------------------------------------------------------------
__global__ __launch_bounds__(256) void stats_kernel(
    const bf16* __restrict__ x, float2* __restrict__ st)
{
  int w = threadIdx.x >> 6, lane = threadIdx.x & 63;
  int tok = blockIdx.x * 4 + w;
  const bf16* xr = x + (size_t)tok * D_;
  float v[6]; float s = 0.f;
#pragma unroll
  for (int j = 0; j < 6; j++) { v[j] = b2f(xr[lane + 64 * j]); s += v[j]; }
#pragma unroll
  for (int o = 1; o < 64; o <<= 1) s += __shfl_xor(s, o, 64);
  float mean = s * (1.0f / D_);
  float sq = 0.f;
#pragma unroll
  for (int j = 0; j < 6; j++) { float d0 = v[j] - mean; sq += d0 * d0; }
#pragma unroll
  for (int o = 1; o < 64; o <<= 1) sq += __shfl_xor(sq, o, 64);
  if (lane == 0) {
    float inv = 1.0f / sqrtf(sq * (1.0f / D_) + 1e-3f);
    st[tok] = make_float2(mean, inv);
  }
}

// ---------------------------------------------------------------------------
// 64-wide MFMA GEMM core (R10/R13-proven). Tile 128m x 64n x 64k.
// ---------------------------------------------------------------------------
#define XS_S 72
#define WT_S 72

template<int AMODE, int RELU, int RESID, int OUTF32, int BIAS>
__device__ __forceinline__ void mgemm_core(
    s16* __restrict__ Xs, s16* __restrict__ Wt,
    const u16* __restrict__ A, const float2* __restrict__ st,
    const u16* __restrict__ lng, const u16* __restrict__ lnb,
    const u16* __restrict__ WT, const bf16* __restrict__ bias,
    const bf16* __restrict__ resid, void* __restrict__ Cout,
    int ldC, int N, int K, int arow0, int crow0, int n0)
{
  int tid = threadIdx.x;
  int w = tid >> 6, lane = tid & 63;
  int quad = lane >> 4, l15 = lane & 15;
  f32x4 acc[2][4];
#pragma unroll
  for (int i = 0; i < 2; i++)
#pragma unroll
    for (int j = 0; j < 4; j++) acc[i][j] = (f32x4){0.f, 0.f, 0.f, 0.f};

  int xr = tid >> 1, xc = (tid & 1) * 32;
  int wn = tid >> 2, wk = (tid & 3) * 16;
  float mean = 0.f, inv = 1.f;
  if (AMODE) { float2 s2 = st[arow0 + xr]; mean = s2.x; inv = s2.y; }
  const u16* Ap0 = A + (size_t)(arow0 + xr) * K + xc;
  bool wvalid = (n0 + wn) < N;
  const u16* Wp0 = WT + (size_t)(wvalid ? (n0 + wn) : 0) * K + wk;

  for (int k0 = 0; k0 < K; k0 += 64) {
    bf16x8 xv[4];
#pragma unroll
    for (int i = 0; i < 4; i++) xv[i] = *(const bf16x8*)(Ap0 + k0 + 8 * i);
    if (AMODE) {
#pragma unroll
      for (int i = 0; i < 4; i++) {
        bf16x8 g = *(const bf16x8*)(lng + xc + k0 + 8 * i);
        bf16x8 b = *(const bf16x8*)(lnb + xc + k0 + 8 * i);
#pragma unroll
        for (int j = 0; j < 8; j++) {
          float f = (u2f((u16)xv[i][j]) - mean) * inv * u2f((u16)g[j])
                  + u2f((u16)b[j]);
          xv[i][j] = (s16)f2u(f);
        }
      }
    }
    bf16x8 wv[2];
#pragma unroll
    for (int i = 0; i < 2; i++)
      wv[i] = wvalid ? *(const bf16x8*)(Wp0 + k0 + 8 * i)
                     : (bf16x8){0,0,0,0,0,0,0,0};
    __syncthreads();
#pragma unroll
    for (int i = 0; i < 4; i++)
      *(bf16x8*)&Xs[xr * XS_S + xc + 8 * i] = xv[i];
#pragma unroll
    for (int i = 0; i < 2; i++)
      *(bf16x8*)&Wt[wn * WT_S + wk + 8 * i] = wv[i];
    __syncthreads();
#pragma unroll
    for (int kh = 0; kh < 2; kh++) {
      int kk = kh * 32 + quad * 8;
      bf16x8 a0 = *(const bf16x8*)&Xs[(w * 32 + l15) * XS_S + kk];
      bf16x8 a1 = *(const bf16x8*)&Xs[(w * 32 + 16 + l15) * XS_S + kk];
#pragma unroll
      for (int nt = 0; nt < 4; nt++) {
        bf16x8 b = *(const bf16x8*)&Wt[(nt * 16 + l15) * WT_S + kk];
        acc[0][nt] = __builtin_amdgcn_mfma_f32_16x16x32_bf16(a0, b, acc[0][nt], 0, 0, 0);
        acc[1][nt] = __builtin_amdgcn_mfma_f32_16x16x32_bf16(a1, b, acc[1][nt], 0, 0, 0);
      }
    }
  }

#pragma unroll
  for (int sub = 0; sub < 2; sub++)
#pragma unroll
    for (int nt = 0; nt < 4; nt++)
#pragma unroll
      for (int r = 0; r < 4; r++) {
        int m = w * 32 + sub * 16 + quad * 4 + r;
        int n = n0 + nt * 16 + l15;
        if (n < N) {
          float v = acc[sub][nt][r];
          if (BIAS)  v += b2f(bias[n]);
          if (RESID) v += b2f(resid[(size_t)(crow0 + m) * ldC + n]);
          if (RELU)  v = fmaxf(v, 0.f);
          if (OUTF32) ((float*)Cout)[(size_t)(crow0 + m) * ldC + n] = v;
          else        ((bf16*)Cout)[(size_t)(crow0 + m) * ldC + n]  = f2b(v);
        }
      }
}

#define MGEMM_LDS __shared__ s16 Xs[128 * XS_S]; __shared__ s16 Wt[64 * WT_S];

// proj (64-wide): chunk-local A, +bias +resid -> x. grid (6, MCc/128).
__global__ __launch_bounds__(256) void proj_mfma(
    const bf16* A, const bf16* Wbuf, bf16* x, int tok0)
{
  MGEMM_LDS
  int n0 = blockIdx.x * 64, m0 = blockIdx.y * 128;
  mgemm_core<0,0,1,0,1>(Xs, Wt, (const u16*)A, nullptr, nullptr, nullptr,
                        (const u16*)Wbuf + OFF_PROJ, (const bf16*)Wbuf + OFF_BPROJ,
                        x, x, D_, D_, D_, m0, tok0 + m0, n0);
}

// ffn2 (64-wide): +bias +resid -> x. grid (6, MCc/128). K=1536.
__global__ __launch_bounds__(256) void ffn2_mfma(
    const bf16* midc, const bf16* Wbuf, bf16* x, int tok0)
{
  MGEMM_LDS
  int n0 = blockIdx.x * 64, m0 = blockIdx.y * 128;
  mgemm_core<0,0,1,0,1>(Xs, Wt, (const u16*)midc, nullptr, nullptr, nullptr,
                        (const u16*)Wbuf + OFF_W2T, (const bf16*)Wbuf + OFF_B2,
                        x, x, D_, D_, 4 * D_, m0, tok0 + m0, n0);
}

// head (64-wide): LNf-fused, f32 out. grid (2, BT/128).
__global__ __launch_bounds__(256) void head_mfma(
    const bf16* x, const float2* st, const bf16* Hbuf, float* out)
{
  MGEMM_LDS
  int n0 = blockIdx.x * 64, m0 = blockIdx.y * 128;
  mgemm_core<1,0,0,1,1>(Xs, Wt, (const u16*)x, st,
                        (const u16*)Hbuf + HOFF_LNFG, (const u16*)Hbuf + HOFF_LNFB,
                        (const u16*)Hbuf + HOFF_WHT, (const bf16*)Hbuf + HOFF_BH,
                        nullptr, out, V_, V_, D_, m0, m0, n0);
}

// ---------------------------------------------------------------------------
// mg128: 128m x 128n x 64k MFMA core (R14-verified). 4 waves own 64x64
// quadrants. Epilogue lambda epi(m_tile_local, n_global, val).
// ---------------------------------------------------------------------------
template<int AMODE, class Epi>
__device__ __forceinline__ void mg128(
    s16* __restrict__ Xs, s16* __restrict__ Ws,
    const u16* __restrict__ A, const float2* __restrict__ st,
    const u16* __restrict__ lng, const u16* __restrict__ lnb,
    const u16* __restrict__ WT, int N, int K, int arow0, int n0, Epi epi)
{
  int tid = threadIdx.x;
  int w = tid >> 6, lane = tid & 63;
  int quad = lane >> 4, l15 = lane & 15;
  int wm = (w >> 1) * 64, wn = (w & 1) * 64;
  f32x4 acc[4][4];
#pragma unroll
  for (int i = 0; i < 4; i++)
#pragma unroll
    for (int j = 0; j < 4; j++) acc[i][j] = (f32x4){0.f, 0.f, 0.f, 0.f};

  int sr = tid >> 1, sc = (tid & 1) * 32;
  float mean = 0.f, inv = 1.f;
  if (AMODE) { float2 s2 = st[arow0 + sr]; mean = s2.x; inv = s2.y; }
  const u16* Ap0 = A + (size_t)(arow0 + sr) * K + sc;
  bool nv = (n0 + sr) < N;
  const u16* Wp0 = WT + (size_t)(nv ? (n0 + sr) : 0) * K + sc;

  for (int k0 = 0; k0 < K; k0 += 64) {
    bf16x8 xv[4], wv[4];
#pragma unroll
    for (int i = 0; i < 4; i++) xv[i] = *(const bf16x8*)(Ap0 + k0 + 8 * i);
    if (AMODE) {
#pragma unroll
      for (int i = 0; i < 4; i++) {
        bf16x8 g = *(const bf16x8*)(lng + sc + k0 + 8 * i);
        bf16x8 b = *(const bf16x8*)(lnb + sc + k0 + 8 * i);
#pragma unroll
        for (int j = 0; j < 8; j++) {
          float f = (u2f((u16)xv[i][j]) - mean) * inv * u2f((u16)g[j])
                  + u2f((u16)b[j]);
          xv[i][j] = (s16)f2u(f);
        }
      }
    }
#pragma unroll
    for (int i = 0; i < 4; i++)
      wv[i] = nv ? *(const bf16x8*)(Wp0 + k0 + 8 * i)
                 : (bf16x8){0,0,0,0,0,0,0,0};
    __syncthreads();
#pragma unroll
    for (int i = 0; i < 4; i++) {
      *(bf16x8*)&Xs[sr * 72 + sc + 8 * i] = xv[i];
      *(bf16x8*)&Ws[sr * 72 + sc + 8 * i] = wv[i];
    }
    __syncthreads();
#pragma unroll
    for (int kh = 0; kh < 2; kh++) {
      int kk = kh * 32 + quad * 8;
      bf16x8 am[4], bn[4];
#pragma unroll
      for (int i = 0; i < 4; i++)
        am[i] = *(const bf16x8*)&Xs[(wm + i * 16 + l15) * 72 + kk];
#pragma unroll
      for (int j = 0; j < 4; j++)
        bn[j] = *(const bf16x8*)&Ws[(wn + j * 16 + l15) * 72 + kk];
#pragma unroll
      for (int i = 0; i < 4; i++)
#pragma unroll
        for (int j = 0; j < 4; j++)
          acc[i][j] = __builtin_amdgcn_mfma_f32_16x16x32_bf16(am[i], bn[j], acc[i][j], 0, 0, 0);
    }
  }

#pragma unroll
  for (int i = 0; i < 4; i++)
#pragma unroll
    for (int j = 0; j < 4; j++)
#pragma unroll
      for (int r = 0; r < 4; r++) {
        int m = wm + i * 16 + quad * 4 + r;
        int n = n0 + wn + j * 16 + l15;
        if (n < N) epi(m, n, acc[i][j][r]);
      }
}

#define MG128_LDS __shared__ s16 Xs[128 * 72]; __shared__ s16 Ws[128 * 72];

// QKV as one GEMM N=1152 (R14-verified). grid (9, MCc/128). LN1-fused.
__global__ __launch_bounds__(256) void qkv128(
    const bf16* x, const float2* st, const bf16* Wbuf, bf16* qkvc,
    int MCa, int tok0)
{
  MG128_LDS
  int n0 = blockIdx.x * 128, mloc0 = blockIdx.y * 128;
  auto epi = [&](int m, int n, float v) {
    int mat = n / 384;
    int rem = n - mat * 384;
    int hh = rem >> 6, hd = rem & 63;
    qkvc[(size_t)mat * MCa * D_ + (size_t)hh * MCa * HD_
         + (size_t)(mloc0 + m) * HD_ + hd] = f2b(v);
  };
  mg128<1>(Xs, Ws, (const u16*)x, st,
           (const u16*)Wbuf + OFF_LN1G, (const u16*)Wbuf + OFF_LN1B,
           (const u16*)Wbuf + OFF_QKV, 1152, D_, tok0 + mloc0, n0, epi);
}

// ffn1 (128-wide, R14-verified): LN2-fused, ReLU -> midc. grid (12, MCc/128).
__global__ __launch_bounds__(256) void ffn1_128(
    const bf16* x, const float2* st, const bf16* Wbuf, bf16* midc, int tok0)
{
  MG128_LDS
  int n0 = blockIdx.x * 128, m0 = blockIdx.y * 128;
  const bf16* bias = (const bf16*)Wbuf + OFF_B1;
  auto epi = [&](int m, int n, float v) {
    float r = v + b2f(bias[n]);
    midc[(size_t)(m0 + m) * (4 * D_) + n] = f2b(fmaxf(r, 0.f));
  };
  mg128<1>(Xs, Ws, (const u16*)x, st,
           (const u16*)Wbuf + OFF_LN2G, (const u16*)Wbuf + OFF_LN2B,
           (const u16*)Wbuf + OFF_W1T, 4 * D_, D_, tok0 + m0, n0, epi);
}

// ---------------------------------------------------------------------------
// MFMA flash attention with online softmax (R13-proven).
// ---------------------------------------------------------------------------
__global__ __launch_bounds__(256) void attn4_kernel(
    const bf16* __restrict__ Q, const bf16* __restrict__ K,
    const bf16* __restrict__ V, bf16* __restrict__ att, int MCa)
{
  __shared__ s16 Qs[64 * 72];
  __shared__ s16 Ks[64 * 72];
  __shared__ s16 Vs[64 * 73];
  __shared__ s16 Ps[4][16 * 72];
  const float scale = 0.05103103630798288f;   // 384^-0.5 (full-D scaling!)
  int tid = threadIdx.x;
  int w = tid >> 6, lane = tid & 63;
  int quad = lane >> 4, l15 = lane & 15;
  int bid = blockIdx.x;
  int qt = bid & 3;
  int bh = bid >> 2;
  int b = bh / H_, h = bh - b * H_;
  size_t base = ((size_t)h * MCa + (size_t)b * T_) * HD_;
  int q0 = qt * 64;
  int cq = qt;

#pragma unroll
  for (int i = 0; i < 2; i++) {
    int e = i * 256 + tid;
    int r = e >> 3, c = (e & 7) * 8;
    *(bf16x8*)&Qs[r * 72 + c] =
        *(const bf16x8*)((const u16*)Q + base + (size_t)(q0 + r) * HD_ + c);
  }

  float mrow[4] = {-1e30f, -1e30f, -1e30f, -1e30f};
  float lrow[4] = {0.f, 0.f, 0.f, 0.f};
  f32x4 O[4];
#pragma unroll
  for (int nt = 0; nt < 4; nt++) O[nt] = (f32x4){0.f, 0.f, 0.f, 0.f};

  for (int c = 0; c <= cq; c++) {
    __syncthreads();
#pragma unroll
    for (int i = 0; i < 2; i++) {
      int e = i * 256 + tid;
      int r = e >> 3, cc = (e & 7) * 8;
      *(bf16x8*)&Ks[r * 72 + cc] =
          *(const bf16x8*)((const u16*)K + base + (size_t)(c * 64 + r) * HD_ + cc);
      bf16x8 vv =
          *(const bf16x8*)((const u16*)V + base + (size_t)(c * 64 + r) * HD_ + cc);
#pragma unroll
      for (int k = 0; k < 8; k++) Vs[r * 73 + cc + k] = vv[k];
    }
    __syncthreads();

    f32x4 S[4];
#pragma unroll
    for (int nt = 0; nt < 4; nt++) S[nt] = (f32x4){0.f, 0.f, 0.f, 0.f};
#pragma unroll
    for (int ks = 0; ks < 2; ks++) {
      int kk = ks * 32 + quad * 8;
      bf16x8 a = *(const bf16x8*)&Qs[(w * 16 + l15) * 72 + kk];
#pragma unroll
      for (int nt = 0; nt < 4; nt++) {
        bf16x8 bb8 = *(const bf16x8*)&Ks[(nt * 16 + l15) * 72 + kk];
        S[nt] = __builtin_amdgcn_mfma_f32_16x16x32_bf16(a, bb8, S[nt], 0, 0, 0);
      }
    }

#pragma unroll
    for (int nt = 0; nt < 4; nt++)
#pragma unroll
      for (int r = 0; r < 4; r++) {
        int qrow = q0 + w * 16 + quad * 4 + r;
        int sg = c * 64 + nt * 16 + l15;
        float v = S[nt][r] * scale;
        S[nt][r] = (sg <= qrow) ? v : -1e30f;
      }

    float alpha[4];
#pragma unroll
    for (int r = 0; r < 4; r++) {
      float mc = fmaxf(fmaxf(S[0][r], S[1][r]), fmaxf(S[2][r], S[3][r]));
#pragma unroll
      for (int o = 1; o < 16; o <<= 1) mc = fmaxf(mc, __shfl_xor(mc, o, 64));
      float mn = fmaxf(mrow[r], mc);
      alpha[r] = __expf(mrow[r] - mn);
      mrow[r] = mn;
      float s = 0.f;
#pragma unroll
      for (int nt = 0; nt < 4; nt++) {
        float p = __expf(S[nt][r] - mn);
        S[nt][r] = p;
        s += p;
      }
#pragma unroll
      for (int o = 1; o < 16; o <<= 1) s += __shfl_xor(s, o, 64);
      lrow[r] = lrow[r] * alpha[r] + s;
    }
#pragma unroll
    for (int nt = 0; nt < 4; nt++)
#pragma unroll
      for (int r = 0; r < 4; r++) O[nt][r] *= alpha[r];

#pragma unroll
    for (int nt = 0; nt < 4; nt++)
#pragma unroll
      for (int r = 0; r < 4; r++)
        Ps[w][(quad * 4 + r) * 72 + nt * 16 + l15] = (s16)f2u(S[nt][r]);
    __syncthreads();
#pragma unroll
    for (int ks = 0; ks < 2; ks++) {
      bf16x8 a = *(const bf16x8*)&Ps[w][l15 * 72 + ks * 32 + quad * 8];
#pragma unroll
      for (int nt = 0; nt < 4; nt++) {
        bf16x8 bb8;
#pragma unroll
        for (int j = 0; j < 8; j++)
          bb8[j] = Vs[(ks * 32 + quad * 8 + j) * 73 + nt * 16 + l15];
        O[nt] = __builtin_amdgcn_mfma_f32_16x16x32_bf16(a, bb8, O[nt], 0, 0, 0);
      }
    }
  }

#pragma unroll
  for (int r = 0; r < 4; r++) {
    float invl = 1.0f / lrow[r];
#pragma unroll
    for (int nt = 0; nt < 4; nt++) {
      int qrow = q0 + w * 16 + quad * 4 + r;
      att[(size_t)(b * T_ + qrow) * D_ + h * HD_ + nt * 16 + l15] =
          f2b(O[nt][r] * invl);
    }
  }
}

// ---------------------------------------------------------------------------
extern "C" void kernel_launch(void* const* d_in, const int* in_sizes, int n_in,
                              void* d_out, int out_size, void* d_ws, size_t ws_size,
                              hipStream_t stream)
{
  float* out = (float*)d_out;
  dim3 blk(256);
  int outg = (out_size + 255) / 256;

  static const int expected[20] = {
      16384, 24960, 98304, 884736, 884736, 884736, 884736, 2304,
      3538944, 9216, 3538944, 2304, 2304, 2304, 2304, 2304, 384, 384,
      24960, 65};
  if (n_in != 20) { const_kernel<<<outg, blk, 0, stream>>>(out, out_size, 5.0f); return; }
  for (int i = 0; i < 20; i++)
    if (in_sizes[i] != expected[i]) {
      const_kernel<<<outg, blk, 0, stream>>>(out, out_size, 10.0f * (i + 1));
      return;
    }
  if (out_size != BT * V_) { const_kernel<<<outg, blk, 0, stream>>>(out, out_size, 7.0f); return; }

  const void* idx   = d_in[0];
  const void* tok   = d_in[1];
  const void* pos   = d_in[2];
  const void* Wq    = d_in[3];
  const void* Wk    = d_in[4];
  const void* Wv    = d_in[5];
  const void* Wproj = d_in[6];
  const void* bproj = d_in[7];
  const void* W1    = d_in[8];
  const void* b1    = d_in[9];
  const void* W2    = d_in[10];
  const void* b2    = d_in[11];
  const void* ln1g  = d_in[12];
  const void* ln1b  = d_in[13];
  const void* ln2g  = d_in[14];
  const void* ln2b  = d_in[15];
  const void* lnfg  = d_in[16];
  const void* lnfb  = d_in[17];
  const void* Whead = d_in[18];
  const void* bhead = d_in[19];

  const size_t off_x  = 256;
  const size_t off_st = off_x + (size_t)BT * D_ * 2;
  const size_t off_wb = off_st + (size_t)BT * 8;
  const size_t off_hb = off_wb + (size_t)WBUF_E * 2;
  const size_t fixed  = off_hb + ((size_t)HBUF_E * 2 + 63) / 64 * 64;
  if (ws_size < fixed) {
    const_kernel<<<outg, blk, 0, stream>>>(out, out_size, 0.0f);
    return;
  }
  size_t region = ws_size - fixed;

  // Single chunk count nc for attention AND ffn:
  //   attention chunk needs qkv(3*MCc*D) + att(MCc*D) = 4*MCc*D bf16
  //   ffn chunk needs mid(MCc*4D) bf16 (overlays the same region)
  // Pick the SMALLEST nc (fewest serialized chunks, biggest grids).
  int nc = 0;
  const int candn[7] = {1, 2, 4, 8, 16, 32, 64};
  for (int i = 0; i < 7; i++)
    if ((size_t)4 * (BT / candn[i]) * D_ * 2 <= region) { nc = candn[i]; break; }
  if (!nc) { const_kernel<<<outg, blk, 0, stream>>>(out, out_size, 0.0f); return; }
  const int MCc = BT / nc;
  const int CBc = MCc / T_;     // sequences per chunk

  char* wsb = (char*)d_ws;
  unsigned* flags = (unsigned*)wsb;
  bf16*   x    = (bf16*)(wsb + off_x);
  float2* st   = (float2*)(wsb + off_st);
  bf16*   Wbuf = (bf16*)(wsb + off_wb);
  bf16*   Hbuf = (bf16*)(wsb + off_hb);
  bf16*   qkvc = (bf16*)(wsb + fixed);
  bf16*   attc = qkvc + (size_t)3 * MCc * D_;
  bf16*   midc = qkvc;                          // overlays qkv+att

  detect_kernel<<<dim3(20), blk, 0, stream>>>(
      tok, pos, Wq, Wk, Wv, Wproj, bproj, W1, b1, W2, b2,
      ln1g, ln1b, ln2g, ln2b, lnfg, lnfb, Whead, bhead,
      (const int*)idx, flags);
  embed_kernel<<<dim3(BT * D_ / 256), blk, 0, stream>>>(idx, tok, pos, x, flags);
  conv_head<<<dim3((HBUF_E + 255) / 256), blk, 0, stream>>>(
      Whead, bhead, lnfg, lnfb, flags, Hbuf);

  for (int l = 0; l < L_; l++) {
    conv_layer<<<dim3((WBUF_E + 255) / 256), blk, 0, stream>>>(
        Wq, Wk, Wv, Wproj, bproj, W1, b1, W2, b2,
        ln1g, ln1b, ln2g, ln2b, flags, Wbuf, l);
    stats_kernel<<<dim3(BT / 4), blk, 0, stream>>>(x, st);
    for (int c = 0; c < nc; c++) {
      int tok0 = c * MCc;
      qkv128<<<dim3(9, MCc / 128), blk, 0, stream>>>(x, st, Wbuf, qkvc, MCc, tok0);
      attn4_kernel<<<dim3(CBc * H_ * 4), blk, 0, stream>>>(
          qkvc, qkvc + (size_t)MCc * D_, qkvc + (size_t)2 * MCc * D_, attc, MCc);
      proj_mfma<<<dim3(6, MCc / 128), blk, 0, stream>>>(attc, Wbuf, x, tok0);
    }
    stats_kernel<<<dim3(BT / 4), blk, 0, stream>>>(x, st);
    for (int f = 0; f < nc; f++) {
      int tok0 = f * MCc;
      ffn1_128<<<dim3(12, MCc / 128), blk, 0, stream>>>(x, st, Wbuf, midc, tok0);
      ffn2_mfma<<<dim3(6, MCc / 128), blk, 0, stream>>>(midc, Wbuf, x, tok0);
    }
  }

  stats_kernel<<<dim3(BT / 4), blk, 0, stream>>>(x, st);
  head_mfma<<<dim3(2, BT / 128), blk, 0, stream>>>(x, st, Hbuf, out);
}

// Round 16
// 1438.828 us; speedup vs baseline: 1.4968x; 1.0542x over previous
//
#include <hip/hip_runtime.h>
#include <hip/hip_bf16.h>

// Problem constants
#define B_  64
#define T_  256
#define D_  384
#define H_  6
#define HD_ 64
#define L_  6
#define V_  65
#define BT  (B_*T_)     // 16384 tokens

typedef __hip_bfloat16 bf16;
typedef unsigned short u16;
typedef short s16;
typedef __attribute__((ext_vector_type(8))) short bf16x8;   // 8 bf16 = 4 VGPR
typedef __attribute__((ext_vector_type(4))) float f32x4;

// Per-layer weight buffer element offsets (bf16 elems)
#define OFF_QKV   0            // rows n = mat*384+h*64+hd, [n][k] 1152x384
#define OFF_PROJ  442368       // [n][k] 384x384
#define OFF_W1T   589824       // [n][k] 1536x384
#define OFF_W2T   1179648      // [n][k] 384x1536
#define OFF_BPROJ 1769472
#define OFF_B1    1769856
#define OFF_B2    1771392
#define OFF_LN1G  1771776
#define OFF_LN1B  1772160
#define OFF_LN2G  1772544
#define OFF_LN2B  1772928
#define WBUF_E    1773312
// Head buffer
#define HOFF_WHT  0            // [n][k] 65x384
#define HOFF_BH   24960
#define HOFF_LNFG 25088
#define HOFF_LNFB 25472
#define HBUF_E    25856

__device__ __forceinline__ float u2f(u16 u) {
  union { unsigned i; float f; } c; c.i = ((unsigned)u) << 16; return c.f;
}
__device__ __forceinline__ bf16 f2b(float x) { return __float2bfloat16(x); }
__device__ __forceinline__ float b2f(bf16 x) { return __bfloat162float(x); }
__device__ __forceinline__ u16 f2u(float x) { bf16 h = f2b(x); return *(u16*)&h; }

__device__ __forceinline__ float pload(const void* p, size_t i, bool f32w) {
  return f32w ? ((const float*)p)[i] : u2f(((const u16*)p)[i]);
}

// ---------------------------------------------------------------------------
// Parallel per-tensor dtype detect (R8-proven).
// ---------------------------------------------------------------------------
__global__ __launch_bounds__(256) void detect_kernel(
    const void* p1,  const void* p2,  const void* p3,  const void* p4,
    const void* p5,  const void* p6,  const void* p7,  const void* p8,
    const void* p9,  const void* p10, const void* p11, const void* p12,
    const void* p13, const void* p14, const void* p15, const void* p16,
    const void* p17, const void* p18, const void* p19,
    const int* __restrict__ idx, unsigned* flags)
{
  const void* ps[20] = {nullptr, p1, p2, p3, p4, p5, p6, p7, p8, p9, p10,
                        p11, p12, p13, p14, p15, p16, p17, p18, p19};
  const int esz[20] = {16384, 24960, 98304, 884736, 884736, 884736, 884736,
                       2304, 3538944, 9216, 3538944, 2304, 2304, 2304, 2304,
                       2304, 384, 384, 24960, 65};
  __shared__ int r1[256], r2[256];
  int bid = blockIdx.x, tid = threadIdx.x;
  if (bid == 19) {
    int z = 0;
    for (int m = tid; m < 4096; m += 256) z += (idx[2 * m + 1] == 0) ? 1 : 0;
    r1[tid] = z; __syncthreads();
    for (int s = 128; s > 0; s >>= 1) {
      if (tid < s) r1[tid] += r1[tid + s];
      __syncthreads();
    }
    if (tid == 0) flags[20] = (r1[0] >= 4000) ? 1u : 0u;
    return;
  }
  int j = bid + 1;
  const u16* p = (const u16*)ps[j];
  int ns = esz[j] / 2; if (ns > 1024) ns = 1024;
  int band = 0, nz = 0;
  for (int i = tid; i < ns; i += 256) {
    u16 lo = p[2 * i], hi = p[2 * i + 1];
    int e = (lo >> 7) & 0xFF;
    band += (e >= 100 && e <= 127) ? 1 : 0;
    nz   += (lo | hi) ? 1 : 0;
  }
  r1[tid] = band; r2[tid] = nz; __syncthreads();
  for (int s = 128; s > 0; s >>= 1) {
    if (tid < s) { r1[tid] += r1[tid + s]; r2[tid] += r2[tid + s]; }
    __syncthreads();
  }
  if (tid == 0) flags[j] = (r2[0] > 0 && r1[0] * 2 < ns) ? 1u : 0u;
}

__global__ void const_kernel(float* out, int n, float val) {
  int i = blockIdx.x * 256 + threadIdx.x;
  if (i < n) out[i] = val;
}

// ---------------------------------------------------------------------------
// Per-layer weight convert+transpose to bf16.
// ---------------------------------------------------------------------------
__global__ __launch_bounds__(256) void conv_layer(
    const void* Wq, const void* Wk, const void* Wv, const void* Wproj,
    const void* bproj, const void* W1, const void* b1, const void* W2,
    const void* b2, const void* ln1g, const void* ln1b, const void* ln2g,
    const void* ln2b, const unsigned* __restrict__ flags,
    bf16* __restrict__ dst, int l)
{
  int e = blockIdx.x * 256 + threadIdx.x;
  if (e >= WBUF_E) return;
  float v;
  if (e < OFF_PROJ) {                       // QKV^T per head
    int math = e / 24576;
    int rem  = e - math * 24576;
    int hd = rem / 384, d = rem - hd * 384;
    int mat = math / 6, hh = math - mat * 6;
    const void* src = (mat == 0 ? Wq : mat == 1 ? Wk : Wv);
    v = pload(src, ((size_t)(l * 6 + hh) * 384 + d) * 64 + hd, flags[3 + mat] != 0);
  } else if (e < OFF_W1T) {                 // Wproj^T
    int e2 = e - OFF_PROJ;
    int n = e2 / 384, d = e2 - n * 384;
    v = pload(Wproj, ((size_t)l * 384 + d) * 384 + n, flags[6] != 0);
  } else if (e < OFF_W2T) {                 // W1^T
    int e2 = e - OFF_W1T;
    int n = e2 / 384, d = e2 - n * 384;
    v = pload(W1, ((size_t)l * 384 + d) * 1536 + n, flags[8] != 0);
  } else if (e < OFF_BPROJ) {               // W2^T
    int e2 = e - OFF_W2T;
    int n = e2 / 1536, k = e2 - n * 1536;
    v = pload(W2, ((size_t)l * 1536 + k) * 384 + n, flags[10] != 0);
  } else {
    int e2 = e - OFF_BPROJ;
    if      (e2 < 384)  v = pload(bproj, (size_t)l * 384 + e2, flags[7] != 0);
    else if (e2 < 1920) v = pload(b1, (size_t)l * 1536 + (e2 - 384), flags[9] != 0);
    else if (e2 < 2304) v = pload(b2, (size_t)l * 384 + (e2 - 1920), flags[11] != 0);
    else if (e2 < 2688) v = pload(ln1g, (size_t)l * 384 + (e2 - 2304), flags[12] != 0);
    else if (e2 < 3072) v = pload(ln1b, (size_t)l * 384 + (e2 - 2688), flags[13] != 0);
    else if (e2 < 3456) v = pload(ln2g, (size_t)l * 384 + (e2 - 3072), flags[14] != 0);
    else                v = pload(ln2b, (size_t)l * 384 + (e2 - 3456), flags[15] != 0);
  }
  dst[e] = f2b(v);
}

__global__ __launch_bounds__(256) void conv_head(
    const void* Wh, const void* bh, const void* lnfg, const void* lnfb,
    const unsigned* __restrict__ flags, bf16* __restrict__ dst)
{
  int e = blockIdx.x * 256 + threadIdx.x;
  if (e >= HBUF_E) return;
  float v = 0.f;
  if (e < HOFF_BH) {                        // Whead^T [65][384]
    int n = e / 384, d = e - n * 384;
    v = pload(Wh, (size_t)d * 65 + n, flags[18] != 0);
  } else if (e < 25025) {
    v = pload(bh, e - HOFF_BH, flags[19] != 0);
  } else if (e < HOFF_LNFG) {
    v = 0.f;
  } else if (e < HOFF_LNFB) {
    v = pload(lnfg, e - HOFF_LNFG, flags[16] != 0);
  } else {
    v = pload(lnfb, e - HOFF_LNFB, flags[17] != 0);
  }
  dst[e] = f2b(v);
}

// ---------------------------------------------------------------------------
__global__ __launch_bounds__(256) void embed_kernel(
    const void* __restrict__ idx, const void* __restrict__ tok,
    const void* __restrict__ pos, bf16* __restrict__ x,
    const unsigned* __restrict__ flags)
{
  int i   = blockIdx.x * 256 + threadIdx.x;   // < BT*D_
  int tkn = i / D_;
  int d   = i - tkn * D_;
  int t   = tkn & (T_ - 1);
  long long tix;
  if (flags[20]) tix = ((const long long*)idx)[tkn];
  else           tix = ((const int*)idx)[tkn];
  float v = pload(tok, (size_t)tix * D_ + d, flags[1] != 0)
          + pload(pos, (size_t)t * D_ + d, flags[2] != 0);
  x[i] = f2b(v);
}

// ---------------------------------------------------------------------------
// LayerNorm: one wave per token. Computes stats (same butterfly as before)
// and writes h = (x-mean)*inv*g + b as bf16 (bit-identical rounding to the
// previous in-register AMODE path). g/b are bf16 (u16) pointers.
// ---------------------------------------------------------------------------
__global__ __launch_bounds__(256) void lnw_kernel(
    const bf16* __restrict__ x, const u16* __restrict__ g,
    const u16* __restrict__ b, bf16* __restrict__ hc, int tok0)
{
  int w = threadIdx.x >> 6, lane = threadIdx.x & 63;
  int lm = blockIdx.x * 4 + w;
  const bf16* xr = x + (size_t)(tok0 + lm) * D_;
  float v[6]; float s = 0.f;
#pragma unroll
  for (int j = 0; j < 6; j++) { v[j] = b2f(xr[lane + 64 * j]); s += v[j]; }
#pragma unroll
  for (int o = 1; o < 64; o <<= 1) s += __shfl_xor(s, o, 64);
  float mean = s * (1.0f / D_);
  float sq = 0.f;
#pragma unroll
  for (int j = 0; j < 6; j++) { float d0 = v[j] - mean; sq += d0 * d0; }
#pragma unroll
  for (int o = 1; o < 64; o <<= 1) sq += __shfl_xor(sq, o, 64);
  float inv = 1.0f / sqrtf(sq * (1.0f / D_) + 1e-3f);
  bf16* hr = hc + (size_t)lm * D_;
#pragma unroll
  for (int j = 0; j < 6; j++) {
    int d = lane + 64 * j;
    hr[d] = f2b((v[j] - mean) * inv * u2f(g[d]) + u2f(b[d]));
  }
}

// ---------------------------------------------------------------------------
// 64-wide MFMA GEMM core (R10/R13-proven). Tile 128m x 64n x 64k. Plain A.
// ---------------------------------------------------------------------------
#define XS_S 72
#define WT_S 72

template<int RELU, int RESID, int OUTF32, int BIAS>
__device__ __forceinline__ void mgemm_core(
    s16* __restrict__ Xs, s16* __restrict__ Wt,
    const u16* __restrict__ A,
    const u16* __restrict__ WT, const bf16* __restrict__ bias,
    const bf16* __restrict__ resid, void* __restrict__ Cout,
    int ldC, int N, int K, int arow0, int crow0, int n0)
{
  int tid = threadIdx.x;
  int w = tid >> 6, lane = tid & 63;
  int quad = lane >> 4, l15 = lane & 15;
  f32x4 acc[2][4];
#pragma unroll
  for (int i = 0; i < 2; i++)
#pragma unroll
    for (int j = 0; j < 4; j++) acc[i][j] = (f32x4){0.f, 0.f, 0.f, 0.f};

  int xr = tid >> 1, xc = (tid & 1) * 32;
  int wn = tid >> 2, wk = (tid & 3) * 16;
  const u16* Ap0 = A + (size_t)(arow0 + xr) * K + xc;
  bool wvalid = (n0 + wn) < N;
  const u16* Wp0 = WT + (size_t)(wvalid ? (n0 + wn) : 0) * K + wk;

  for (int k0 = 0; k0 < K; k0 += 64) {
    bf16x8 xv[4];
#pragma unroll
    for (int i = 0; i < 4; i++) xv[i] = *(const bf16x8*)(Ap0 + k0 + 8 * i);
    bf16x8 wv[2];
#pragma unroll
    for (int i = 0; i < 2; i++)
      wv[i] = wvalid ? *(const bf16x8*)(Wp0 + k0 + 8 * i)
                     : (bf16x8){0,0,0,0,0,0,0,0};
    __syncthreads();
#pragma unroll
    for (int i = 0; i < 4; i++)
      *(bf16x8*)&Xs[xr * XS_S + xc + 8 * i] = xv[i];
#pragma unroll
    for (int i = 0; i < 2; i++)
      *(bf16x8*)&Wt[wn * WT_S + wk + 8 * i] = wv[i];
    __syncthreads();
#pragma unroll
    for (int kh = 0; kh < 2; kh++) {
      int kk = kh * 32 + quad * 8;
      bf16x8 a0 = *(const bf16x8*)&Xs[(w * 32 + l15) * XS_S + kk];
      bf16x8 a1 = *(const bf16x8*)&Xs[(w * 32 + 16 + l15) * XS_S + kk];
#pragma unroll
      for (int nt = 0; nt < 4; nt++) {
        bf16x8 b = *(const bf16x8*)&Wt[(nt * 16 + l15) * WT_S + kk];
        acc[0][nt] = __builtin_amdgcn_mfma_f32_16x16x32_bf16(a0, b, acc[0][nt], 0, 0, 0);
        acc[1][nt] = __builtin_amdgcn_mfma_f32_16x16x32_bf16(a1, b, acc[1][nt], 0, 0, 0);
      }
    }
  }

#pragma unroll
  for (int sub = 0; sub < 2; sub++)
#pragma unroll
    for (int nt = 0; nt < 4; nt++)
#pragma unroll
      for (int r = 0; r < 4; r++) {
        int m = w * 32 + sub * 16 + quad * 4 + r;
        int n = n0 + nt * 16 + l15;
        if (n < N) {
          float v = acc[sub][nt][r];
          if (BIAS)  v += b2f(bias[n]);
          if (RESID) v += b2f(resid[(size_t)(crow0 + m) * ldC + n]);
          if (RELU)  v = fmaxf(v, 0.f);
          if (OUTF32) ((float*)Cout)[(size_t)(crow0 + m) * ldC + n] = v;
          else        ((bf16*)Cout)[(size_t)(crow0 + m) * ldC + n]  = f2b(v);
        }
      }
}

#define MGEMM_LDS __shared__ s16 Xs[128 * XS_S]; __shared__ s16 Wt[64 * WT_S];

// proj (64-wide): chunk-local A, +bias +resid -> x. grid (6, MCc/128).
__global__ __launch_bounds__(256) void proj_mfma(
    const bf16* A, const bf16* Wbuf, bf16* x, int tok0)
{
  MGEMM_LDS
  int n0 = blockIdx.x * 64, m0 = blockIdx.y * 128;
  mgemm_core<0,1,0,1>(Xs, Wt, (const u16*)A,
                      (const u16*)Wbuf + OFF_PROJ, (const bf16*)Wbuf + OFF_BPROJ,
                      x, x, D_, D_, D_, m0, tok0 + m0, n0);
}

// ffn2 (64-wide): +bias +resid -> x. grid (6, MCc/128). K=1536.
__global__ __launch_bounds__(256) void ffn2_mfma(
    const bf16* midc, const bf16* Wbuf, bf16* x, int tok0)
{
  MGEMM_LDS
  int n0 = blockIdx.x * 64, m0 = blockIdx.y * 128;
  mgemm_core<0,1,0,1>(Xs, Wt, (const u16*)midc,
                      (const u16*)Wbuf + OFF_W2T, (const bf16*)Wbuf + OFF_B2,
                      x, x, D_, D_, 4 * D_, m0, tok0 + m0, n0);
}

// head (64-wide): plain A = hc (chunk-local), f32 out rows tok0+m.
__global__ __launch_bounds__(256) void head_mfma(
    const bf16* hc, const bf16* Hbuf, float* out, int tok0)
{
  MGEMM_LDS
  int n0 = blockIdx.x * 64, m0 = blockIdx.y * 128;
  mgemm_core<0,0,1,1>(Xs, Wt, (const u16*)hc,
                      (const u16*)Hbuf + HOFF_WHT, (const bf16*)Hbuf + HOFF_BH,
                      nullptr, out, V_, V_, D_, m0, tok0 + m0, n0);
}

// ---------------------------------------------------------------------------
// mg128: 128m x 128n x 64k MFMA core (R14-verified), plain A.
// Epilogue lambda epi(m_tile_local, n_global, val).
// ---------------------------------------------------------------------------
template<class Epi>
__device__ __forceinline__ void mg128(
    s16* __restrict__ Xs, s16* __restrict__ Ws,
    const u16* __restrict__ A,
    const u16* __restrict__ WT, int N, int K, int arow0, int n0, Epi epi)
{
  int tid = threadIdx.x;
  int w = tid >> 6, lane = tid & 63;
  int quad = lane >> 4, l15 = lane & 15;
  int wm = (w >> 1) * 64, wn = (w & 1) * 64;
  f32x4 acc[4][4];
#pragma unroll
  for (int i = 0; i < 4; i++)
#pragma unroll
    for (int j = 0; j < 4; j++) acc[i][j] = (f32x4){0.f, 0.f, 0.f, 0.f};

  int sr = tid >> 1, sc = (tid & 1) * 32;
  const u16* Ap0 = A + (size_t)(arow0 + sr) * K + sc;
  bool nv = (n0 + sr) < N;
  const u16* Wp0 = WT + (size_t)(nv ? (n0 + sr) : 0) * K + sc;

  for (int k0 = 0; k0 < K; k0 += 64) {
    bf16x8 xv[4], wv[4];
#pragma unroll
    for (int i = 0; i < 4; i++) xv[i] = *(const bf16x8*)(Ap0 + k0 + 8 * i);
#pragma unroll
    for (int i = 0; i < 4; i++)
      wv[i] = nv ? *(const bf16x8*)(Wp0 + k0 + 8 * i)
                 : (bf16x8){0,0,0,0,0,0,0,0};
    __syncthreads();
#pragma unroll
    for (int i = 0; i < 4; i++) {
      *(bf16x8*)&Xs[sr * 72 + sc + 8 * i] = xv[i];
      *(bf16x8*)&Ws[sr * 72 + sc + 8 * i] = wv[i];
    }
    __syncthreads();
#pragma unroll
    for (int kh = 0; kh < 2; kh++) {
      int kk = kh * 32 + quad * 8;
      bf16x8 am[4], bn[4];
#pragma unroll
      for (int i = 0; i < 4; i++)
        am[i] = *(const bf16x8*)&Xs[(wm + i * 16 + l15) * 72 + kk];
#pragma unroll
      for (int j = 0; j < 4; j++)
        bn[j] = *(const bf16x8*)&Ws[(wn + j * 16 + l15) * 72 + kk];
#pragma unroll
      for (int i = 0; i < 4; i++)
#pragma unroll
        for (int j = 0; j < 4; j++)
          acc[i][j] = __builtin_amdgcn_mfma_f32_16x16x32_bf16(am[i], bn[j], acc[i][j], 0, 0, 0);
    }
  }

#pragma unroll
  for (int i = 0; i < 4; i++)
#pragma unroll
    for (int j = 0; j < 4; j++)
#pragma unroll
      for (int r = 0; r < 4; r++) {
        int m = wm + i * 16 + quad * 4 + r;
        int n = n0 + wn + j * 16 + l15;
        if (n < N) epi(m, n, acc[i][j][r]);
      }
}

#define MG128_LDS __shared__ s16 Xs[128 * 72]; __shared__ s16 Ws[128 * 72];

// QKV as one GEMM N=1152 (R14-verified scatter). Plain A = hc (chunk-local).
// grid (9, MCc/128).
__global__ __launch_bounds__(256) void qkv128(
    const bf16* hc, const bf16* Wbuf, bf16* qkvc, int MCa)
{
  MG128_LDS
  int n0 = blockIdx.x * 128, mloc0 = blockIdx.y * 128;
  auto epi = [&](int m, int n, float v) {
    int mat = n / 384;
    int rem = n - mat * 384;
    int hh = rem >> 6, hd = rem & 63;
    qkvc[(size_t)mat * MCa * D_ + (size_t)hh * MCa * HD_
         + (size_t)(mloc0 + m) * HD_ + hd] = f2b(v);
  };
  mg128(Xs, Ws, (const u16*)hc,
        (const u16*)Wbuf + OFF_QKV, 1152, D_, mloc0, n0, epi);
}

// ffn1 (128-wide): plain A = hc (chunk-local), ReLU -> midc. grid (12, MCc/128).
__global__ __launch_bounds__(256) void ffn1_128(
    const bf16* hc, const bf16* Wbuf, bf16* midc)
{
  MG128_LDS
  int n0 = blockIdx.x * 128, m0 = blockIdx.y * 128;
  const bf16* bias = (const bf16*)Wbuf + OFF_B1;
  auto epi = [&](int m, int n, float v) {
    float r = v + b2f(bias[n]);
    midc[(size_t)(m0 + m) * (4 * D_) + n] = f2b(fmaxf(r, 0.f));
  };
  mg128(Xs, Ws, (const u16*)hc,
        (const u16*)Wbuf + OFF_W1T, 4 * D_, D_, m0, n0, epi);
}

// ---------------------------------------------------------------------------
// MFMA flash attention with online softmax (R13-proven).
// ---------------------------------------------------------------------------
__global__ __launch_bounds__(256) void attn4_kernel(
    const bf16* __restrict__ Q, const bf16* __restrict__ K,
    const bf16* __restrict__ V, bf16* __restrict__ att, int MCa)
{
  __shared__ s16 Qs[64 * 72];
  __shared__ s16 Ks[64 * 72];
  __shared__ s16 Vs[64 * 73];
  __shared__ s16 Ps[4][16 * 72];
  const float scale = 0.05103103630798288f;   // 384^-0.5 (full-D scaling!)
  int tid = threadIdx.x;
  int w = tid >> 6, lane = tid & 63;
  int quad = lane >> 4, l15 = lane & 15;
  int bid = blockIdx.x;
  int qt = bid & 3;
  int bh = bid >> 2;
  int b = bh / H_, h = bh - b * H_;
  size_t base = ((size_t)h * MCa + (size_t)b * T_) * HD_;
  int q0 = qt * 64;
  int cq = qt;

#pragma unroll
  for (int i = 0; i < 2; i++) {
    int e = i * 256 + tid;
    int r = e >> 3, c = (e & 7) * 8;
    *(bf16x8*)&Qs[r * 72 + c] =
        *(const bf16x8*)((const u16*)Q + base + (size_t)(q0 + r) * HD_ + c);
  }

  float mrow[4] = {-1e30f, -1e30f, -1e30f, -1e30f};
  float lrow[4] = {0.f, 0.f, 0.f, 0.f};
  f32x4 O[4];
#pragma unroll
  for (int nt = 0; nt < 4; nt++) O[nt] = (f32x4){0.f, 0.f, 0.f, 0.f};

  for (int c = 0; c <= cq; c++) {
    __syncthreads();
#pragma unroll
    for (int i = 0; i < 2; i++) {
      int e = i * 256 + tid;
      int r = e >> 3, cc = (e & 7) * 8;
      *(bf16x8*)&Ks[r * 72 + cc] =
          *(const bf16x8*)((const u16*)K + base + (size_t)(c * 64 + r) * HD_ + cc);
      bf16x8 vv =
          *(const bf16x8*)((const u16*)V + base + (size_t)(c * 64 + r) * HD_ + cc);
#pragma unroll
      for (int k = 0; k < 8; k++) Vs[r * 73 + cc + k] = vv[k];
    }
    __syncthreads();

    f32x4 S[4];
#pragma unroll
    for (int nt = 0; nt < 4; nt++) S[nt] = (f32x4){0.f, 0.f, 0.f, 0.f};
#pragma unroll
    for (int ks = 0; ks < 2; ks++) {
      int kk = ks * 32 + quad * 8;
      bf16x8 a = *(const bf16x8*)&Qs[(w * 16 + l15) * 72 + kk];
#pragma unroll
      for (int nt = 0; nt < 4; nt++) {
        bf16x8 bb8 = *(const bf16x8*)&Ks[(nt * 16 + l15) * 72 + kk];
        S[nt] = __builtin_amdgcn_mfma_f32_16x16x32_bf16(a, bb8, S[nt], 0, 0, 0);
      }
    }

#pragma unroll
    for (int nt = 0; nt < 4; nt++)
#pragma unroll
      for (int r = 0; r < 4; r++) {
        int qrow = q0 + w * 16 + quad * 4 + r;
        int sg = c * 64 + nt * 16 + l15;
        float v = S[nt][r] * scale;
        S[nt][r] = (sg <= qrow) ? v : -1e30f;
      }

    float alpha[4];
#pragma unroll
    for (int r = 0; r < 4; r++) {
      float mc = fmaxf(fmaxf(S[0][r], S[1][r]), fmaxf(S[2][r], S[3][r]));
#pragma unroll
      for (int o = 1; o < 16; o <<= 1) mc = fmaxf(mc, __shfl_xor(mc, o, 64));
      float mn = fmaxf(mrow[r], mc);
      alpha[r] = __expf(mrow[r] - mn);
      mrow[r] = mn;
      float s = 0.f;
#pragma unroll
      for (int nt = 0; nt < 4; nt++) {
        float p = __expf(S[nt][r] - mn);
        S[nt][r] = p;
        s += p;
      }
#pragma unroll
      for (int o = 1; o < 16; o <<= 1) s += __shfl_xor(s, o, 64);
      lrow[r] = lrow[r] * alpha[r] + s;
    }
#pragma unroll
    for (int nt = 0; nt < 4; nt++)
#pragma unroll
      for (int r = 0; r < 4; r++) O[nt][r] *= alpha[r];

#pragma unroll
    for (int nt = 0; nt < 4; nt++)
#pragma unroll
      for (int r = 0; r < 4; r++)
        Ps[w][(quad * 4 + r) * 72 + nt * 16 + l15] = (s16)f2u(S[nt][r]);
    __syncthreads();
#pragma unroll
    for (int ks = 0; ks < 2; ks++) {
      bf16x8 a = *(const bf16x8*)&Ps[w][l15 * 72 + ks * 32 + quad * 8];
#pragma unroll
      for (int nt = 0; nt < 4; nt++) {
        bf16x8 bb8;
#pragma unroll
        for (int j = 0; j < 8; j++)
          bb8[j] = Vs[(ks * 32 + quad * 8 + j) * 73 + nt * 16 + l15];
        O[nt] = __builtin_amdgcn_mfma_f32_16x16x32_bf16(a, bb8, O[nt], 0, 0, 0);
      }
    }
  }

#pragma unroll
  for (int r = 0; r < 4; r++) {
    float invl = 1.0f / lrow[r];
#pragma unroll
    for (int nt = 0; nt < 4; nt++) {
      int qrow = q0 + w * 16 + quad * 4 + r;
      att[(size_t)(b * T_ + qrow) * D_ + h * HD_ + nt * 16 + l15] =
          f2b(O[nt][r] * invl);
    }
  }
}

// ---------------------------------------------------------------------------
extern "C" void kernel_launch(void* const* d_in, const int* in_sizes, int n_in,
                              void* d_out, int out_size, void* d_ws, size_t ws_size,
                              hipStream_t stream)
{
  float* out = (float*)d_out;
  dim3 blk(256);
  int outg = (out_size + 255) / 256;

  static const int expected[20] = {
      16384, 24960, 98304, 884736, 884736, 884736, 884736, 2304,
      3538944, 9216, 3538944, 2304, 2304, 2304, 2304, 2304, 384, 384,
      24960, 65};
  if (n_in != 20) { const_kernel<<<outg, blk, 0, stream>>>(out, out_size, 5.0f); return; }
  for (int i = 0; i < 20; i++)
    if (in_sizes[i] != expected[i]) {
      const_kernel<<<outg, blk, 0, stream>>>(out, out_size, 10.0f * (i + 1));
      return;
    }
  if (out_size != BT * V_) { const_kernel<<<outg, blk, 0, stream>>>(out, out_size, 7.0f); return; }

  const void* idx   = d_in[0];
  const void* tok   = d_in[1];
  const void* pos   = d_in[2];
  const void* Wq    = d_in[3];
  const void* Wk    = d_in[4];
  const void* Wv    = d_in[5];
  const void* Wproj = d_in[6];
  const void* bproj = d_in[7];
  const void* W1    = d_in[8];
  const void* b1    = d_in[9];
  const void* W2    = d_in[10];
  const void* b2    = d_in[11];
  const void* ln1g  = d_in[12];
  const void* ln1b  = d_in[13];
  const void* ln2g  = d_in[14];
  const void* ln2b  = d_in[15];
  const void* lnfg  = d_in[16];
  const void* lnfb  = d_in[17];
  const void* Whead = d_in[18];
  const void* bhead = d_in[19];

  const size_t off_x  = 256;
  const size_t off_wb = off_x + (size_t)BT * D_ * 2;
  const size_t off_hb = off_wb + (size_t)WBUF_E * 2;
  const size_t fixed  = off_hb + ((size_t)HBUF_E * 2 + 63) / 64 * 64;
  if (ws_size < fixed) {
    const_kernel<<<outg, blk, 0, stream>>>(out, out_size, 0.0f);
    return;
  }
  size_t region = ws_size - fixed;

  // Chunk region = 5 units of MCc*D bf16:
  //   attn phase: hc | qkv(3) | att(1)
  //   ffn  phase: hc | mid(4)   (mid overlays qkv+att)
  int nc = 0;
  const int candn[7] = {1, 2, 4, 8, 16, 32, 64};
  for (int i = 0; i < 7; i++)
    if ((size_t)5 * (BT / candn[i]) * D_ * 2 <= region) { nc = candn[i]; break; }
  if (!nc) { const_kernel<<<outg, blk, 0, stream>>>(out, out_size, 0.0f); return; }
  const int MCc = BT / nc;
  const int CBc = MCc / T_;     // sequences per chunk

  char* wsb = (char*)d_ws;
  unsigned* flags = (unsigned*)wsb;
  bf16*   x    = (bf16*)(wsb + off_x);
  bf16*   Wbuf = (bf16*)(wsb + off_wb);
  bf16*   Hbuf = (bf16*)(wsb + off_hb);
  bf16*   hc   = (bf16*)(wsb + fixed);
  bf16*   qkvc = hc + (size_t)MCc * D_;
  bf16*   attc = qkvc + (size_t)3 * MCc * D_;
  bf16*   midc = qkvc;                          // overlays qkv+att

  detect_kernel<<<dim3(20), blk, 0, stream>>>(
      tok, pos, Wq, Wk, Wv, Wproj, bproj, W1, b1, W2, b2,
      ln1g, ln1b, ln2g, ln2b, lnfg, lnfb, Whead, bhead,
      (const int*)idx, flags);
  embed_kernel<<<dim3(BT * D_ / 256), blk, 0, stream>>>(idx, tok, pos, x, flags);
  conv_head<<<dim3((HBUF_E + 255) / 256), blk, 0, stream>>>(
      Whead, bhead, lnfg, lnfb, flags, Hbuf);

  for (int l = 0; l < L_; l++) {
    conv_layer<<<dim3((WBUF_E + 255) / 256), blk, 0, stream>>>(
        Wq, Wk, Wv, Wproj, bproj, W1, b1, W2, b2,
        ln1g, ln1b, ln2g, ln2b, flags, Wbuf, l);
    for (int c = 0; c < nc; c++) {
      int tok0 = c * MCc;
      lnw_kernel<<<dim3(MCc / 4), blk, 0, stream>>>(
          x, (const u16*)Wbuf + OFF_LN1G, (const u16*)Wbuf + OFF_LN1B, hc, tok0);
      qkv128<<<dim3(9, MCc / 128), blk, 0, stream>>>(hc, Wbuf, qkvc, MCc);
      attn4_kernel<<<dim3(CBc * H_ * 4), blk, 0, stream>>>(
          qkvc, qkvc + (size_t)MCc * D_, qkvc + (size_t)2 * MCc * D_, attc, MCc);
      proj_mfma<<<dim3(6, MCc / 128), blk, 0, stream>>>(attc, Wbuf, x, tok0);
    }
    for (int f = 0; f < nc; f++) {
      int tok0 = f * MCc;
      lnw_kernel<<<dim3(MCc / 4), blk, 0, stream>>>(
          x, (const u16*)Wbuf + OFF_LN2G, (const u16*)Wbuf + OFF_LN2B, hc, tok0);
      ffn1_128<<<dim3(12, MCc / 128), blk, 0, stream>>>(hc, Wbuf, midc);
      ffn2_mfma<<<dim3(6, MCc / 128), blk, 0, stream>>>(midc, Wbuf, x, tok0);
    }
  }

  for (int c = 0; c < nc; c++) {
    int tok0 = c * MCc;
    lnw_kernel<<<dim3(MCc / 4), blk, 0, stream>>>(
        x, (const u16*)Hbuf + HOFF_LNFG, (const u16*)Hbuf + HOFF_LNFB, hc, tok0);
    head_mfma<<<dim3(2, MCc / 128), blk, 0, stream>>>(hc, Hbuf, out, tok0);
  }
}

// Round 17
// 1275.607 us; speedup vs baseline: 1.6883x; 1.1280x over previous
//
#include <hip/hip_runtime.h>
#include <hip/hip_bf16.h>

// Problem constants
#define B_  64
#define T_  256
#define D_  384
#define H_  6
#define HD_ 64
#define L_  6
#define V_  65
#define BT  (B_*T_)     // 16384 tokens

typedef __hip_bfloat16 bf16;
typedef unsigned short u16;
typedef short s16;
typedef __attribute__((ext_vector_type(8))) short bf16x8;   // 8 bf16 = 4 VGPR
typedef __attribute__((ext_vector_type(4))) float f32x4;

// Per-layer weight buffer element offsets (bf16 elems)
#define OFF_QKV   0            // rows n = mat*384+h*64+hd, [n][k] 1152x384
#define OFF_PROJ  442368       // [n][k] 384x384
#define OFF_W1T   589824       // [n][k] 1536x384
#define OFF_W2T   1179648      // [n][k] 384x1536
#define OFF_BPROJ 1769472
#define OFF_B1    1769856
#define OFF_B2    1771392
#define OFF_LN1G  1771776
#define OFF_LN1B  1772160
#define OFF_LN2G  1772544
#define OFF_LN2B  1772928
#define WBUF_E    1773312
// Head buffer
#define HOFF_WHT  0            // [n][k] 65x384
#define HOFF_BH   24960
#define HOFF_LNFG 25088
#define HOFF_LNFB 25472
#define HBUF_E    25856

__device__ __forceinline__ float u2f(u16 u) {
  union { unsigned i; float f; } c; c.i = ((unsigned)u) << 16; return c.f;
}
__device__ __forceinline__ bf16 f2b(float x) { return __float2bfloat16(x); }
__device__ __forceinline__ float b2f(bf16 x) { return __bfloat162float(x); }
__device__ __forceinline__ u16 f2u(float x) { bf16 h = f2b(x); return *(u16*)&h; }

__device__ __forceinline__ float pload(const void* p, size_t i, bool f32w) {
  return f32w ? ((const float*)p)[i] : u2f(((const u16*)p)[i]);
}

// XCD-aware swizzle: all n-tiles of one m-tile get block ids congruent mod 8
// -> same XCD -> A-row re-reads hit that XCD's L2. [guide §1: locality only]
__device__ __forceinline__ void swz(int gid, int ntc, int mtiles,
                                    int& nt, int& mblk) {
  if ((mtiles & 7) == 0) {
    int per = ntc << 3;            // 8 m-tiles per group
    int g   = gid / per;
    int rem = gid - g * per;
    nt   = rem >> 3;
    mblk = (g << 3) + (rem & 7);
  } else {
    nt   = gid / mtiles;
    mblk = gid - nt * mtiles;
  }
}

// ---------------------------------------------------------------------------
// Parallel per-tensor dtype detect (R8-proven).
// ---------------------------------------------------------------------------
__global__ __launch_bounds__(256) void detect_kernel(
    const void* p1,  const void* p2,  const void* p3,  const void* p4,
    const void* p5,  const void* p6,  const void* p7,  const void* p8,
    const void* p9,  const void* p10, const void* p11, const void* p12,
    const void* p13, const void* p14, const void* p15, const void* p16,
    const void* p17, const void* p18, const void* p19,
    const int* __restrict__ idx, unsigned* flags)
{
  const void* ps[20] = {nullptr, p1, p2, p3, p4, p5, p6, p7, p8, p9, p10,
                        p11, p12, p13, p14, p15, p16, p17, p18, p19};
  const int esz[20] = {16384, 24960, 98304, 884736, 884736, 884736, 884736,
                       2304, 3538944, 9216, 3538944, 2304, 2304, 2304, 2304,
                       2304, 384, 384, 24960, 65};
  __shared__ int r1[256], r2[256];
  int bid = blockIdx.x, tid = threadIdx.x;
  if (bid == 19) {
    int z = 0;
    for (int m = tid; m < 4096; m += 256) z += (idx[2 * m + 1] == 0) ? 1 : 0;
    r1[tid] = z; __syncthreads();
    for (int s = 128; s > 0; s >>= 1) {
      if (tid < s) r1[tid] += r1[tid + s];
      __syncthreads();
    }
    if (tid == 0) flags[20] = (r1[0] >= 4000) ? 1u : 0u;
    return;
  }
  int j = bid + 1;
  const u16* p = (const u16*)ps[j];
  int ns = esz[j] / 2; if (ns > 1024) ns = 1024;
  int band = 0, nz = 0;
  for (int i = tid; i < ns; i += 256) {
    u16 lo = p[2 * i], hi = p[2 * i + 1];
    int e = (lo >> 7) & 0xFF;
    band += (e >= 100 && e <= 127) ? 1 : 0;
    nz   += (lo | hi) ? 1 : 0;
  }
  r1[tid] = band; r2[tid] = nz; __syncthreads();
  for (int s = 128; s > 0; s >>= 1) {
    if (tid < s) { r1[tid] += r1[tid + s]; r2[tid] += r2[tid + s]; }
    __syncthreads();
  }
  if (tid == 0) flags[j] = (r2[0] > 0 && r1[0] * 2 < ns) ? 1u : 0u;
}

__global__ void const_kernel(float* out, int n, float val) {
  int i = blockIdx.x * 256 + threadIdx.x;
  if (i < n) out[i] = val;
}

// ---------------------------------------------------------------------------
// Per-layer weight convert+transpose to bf16.
// ---------------------------------------------------------------------------
__global__ __launch_bounds__(256) void conv_layer(
    const void* Wq, const void* Wk, const void* Wv, const void* Wproj,
    const void* bproj, const void* W1, const void* b1, const void* W2,
    const void* b2, const void* ln1g, const void* ln1b, const void* ln2g,
    const void* ln2b, const unsigned* __restrict__ flags,
    bf16* __restrict__ dst, int l)
{
  int e = blockIdx.x * 256 + threadIdx.x;
  if (e >= WBUF_E) return;
  float v;
  if (e < OFF_PROJ) {                       // QKV^T per head
    int math = e / 24576;
    int rem  = e - math * 24576;
    int hd = rem / 384, d = rem - hd * 384;
    int mat = math / 6, hh = math - mat * 6;
    const void* src = (mat == 0 ? Wq : mat == 1 ? Wk : Wv);
    v = pload(src, ((size_t)(l * 6 + hh) * 384 + d) * 64 + hd, flags[3 + mat] != 0);
  } else if (e < OFF_W1T) {                 // Wproj^T
    int e2 = e - OFF_PROJ;
    int n = e2 / 384, d = e2 - n * 384;
    v = pload(Wproj, ((size_t)l * 384 + d) * 384 + n, flags[6] != 0);
  } else if (e < OFF_W2T) {                 // W1^T
    int e2 = e - OFF_W1T;
    int n = e2 / 384, d = e2 - n * 384;
    v = pload(W1, ((size_t)l * 384 + d) * 1536 + n, flags[8] != 0);
  } else if (e < OFF_BPROJ) {               // W2^T
    int e2 = e - OFF_W2T;
    int n = e2 / 1536, k = e2 - n * 1536;
    v = pload(W2, ((size_t)l * 1536 + k) * 384 + n, flags[10] != 0);
  } else {
    int e2 = e - OFF_BPROJ;
    if      (e2 < 384)  v = pload(bproj, (size_t)l * 384 + e2, flags[7] != 0);
    else if (e2 < 1920) v = pload(b1, (size_t)l * 1536 + (e2 - 384), flags[9] != 0);
    else if (e2 < 2304) v = pload(b2, (size_t)l * 384 + (e2 - 1920), flags[11] != 0);
    else if (e2 < 2688) v = pload(ln1g, (size_t)l * 384 + (e2 - 2304), flags[12] != 0);
    else if (e2 < 3072) v = pload(ln1b, (size_t)l * 384 + (e2 - 2688), flags[13] != 0);
    else if (e2 < 3456) v = pload(ln2g, (size_t)l * 384 + (e2 - 3072), flags[14] != 0);
    else                v = pload(ln2b, (size_t)l * 384 + (e2 - 3456), flags[15] != 0);
  }
  dst[e] = f2b(v);
}

__global__ __launch_bounds__(256) void conv_head(
    const void* Wh, const void* bh, const void* lnfg, const void* lnfb,
    const unsigned* __restrict__ flags, bf16* __restrict__ dst)
{
  int e = blockIdx.x * 256 + threadIdx.x;
  if (e >= HBUF_E) return;
  float v = 0.f;
  if (e < HOFF_BH) {                        // Whead^T [65][384]
    int n = e / 384, d = e - n * 384;
    v = pload(Wh, (size_t)d * 65 + n, flags[18] != 0);
  } else if (e < 25025) {
    v = pload(bh, e - HOFF_BH, flags[19] != 0);
  } else if (e < HOFF_LNFG) {
    v = 0.f;
  } else if (e < HOFF_LNFB) {
    v = pload(lnfg, e - HOFF_LNFG, flags[16] != 0);
  } else {
    v = pload(lnfb, e - HOFF_LNFB, flags[17] != 0);
  }
  dst[e] = f2b(v);
}

// ---------------------------------------------------------------------------
__global__ __launch_bounds__(256) void embed_kernel(
    const void* __restrict__ idx, const void* __restrict__ tok,
    const void* __restrict__ pos, bf16* __restrict__ x,
    const unsigned* __restrict__ flags)
{
  int i   = blockIdx.x * 256 + threadIdx.x;   // < BT*D_
  int tkn = i / D_;
  int d   = i - tkn * D_;
  int t   = tkn & (T_ - 1);
  long long tix;
  if (flags[20]) tix = ((const long long*)idx)[tkn];
  else           tix = ((const int*)idx)[tkn];
  float v = pload(tok, (size_t)tix * D_ + d, flags[1] != 0)
          + pload(pos, (size_t)t * D_ + d, flags[2] != 0);
  x[i] = f2b(v);
}

// ---------------------------------------------------------------------------
// LayerNorm: one wave per token -> hc (chunk-local). R16-proven.
// ---------------------------------------------------------------------------
__global__ __launch_bounds__(256) void lnw_kernel(
    const bf16* __restrict__ x, const u16* __restrict__ g,
    const u16* __restrict__ b, bf16* __restrict__ hc, int tok0)
{
  int w = threadIdx.x >> 6, lane = threadIdx.x & 63;
  int lm = blockIdx.x * 4 + w;
  const bf16* xr = x + (size_t)(tok0 + lm) * D_;
  float v[6]; float s = 0.f;
#pragma unroll
  for (int j = 0; j < 6; j++) { v[j] = b2f(xr[lane + 64 * j]); s += v[j]; }
#pragma unroll
  for (int o = 1; o < 64; o <<= 1) s += __shfl_xor(s, o, 64);
  float mean = s * (1.0f / D_);
  float sq = 0.f;
#pragma unroll
  for (int j = 0; j < 6; j++) { float d0 = v[j] - mean; sq += d0 * d0; }
#pragma unroll
  for (int o = 1; o < 64; o <<= 1) sq += __shfl_xor(sq, o, 64);
  float inv = 1.0f / sqrtf(sq * (1.0f / D_) + 1e-3f);
  bf16* hr = hc + (size_t)lm * D_;
#pragma unroll
  for (int j = 0; j < 6; j++) {
    int d = lane + 64 * j;
    hr[d] = f2b((v[j] - mean) * inv * u2f(g[d]) + u2f(b[d]));
  }
}

// ---------------------------------------------------------------------------
// 64-wide MFMA GEMM core (R10/R13-proven). Tile 128m x 64n x 64k. Plain A.
// ---------------------------------------------------------------------------
#define XS_S 72
#define WT_S 72

template<int RELU, int RESID, int OUTF32, int BIAS>
__device__ __forceinline__ void mgemm_core(
    s16* __restrict__ Xs, s16* __restrict__ Wt,
    const u16* __restrict__ A,
    const u16* __restrict__ WT, const bf16* __restrict__ bias,
    const bf16* __restrict__ resid, void* __restrict__ Cout,
    int ldC, int N, int K, int arow0, int crow0, int n0)
{
  int tid = threadIdx.x;
  int w = tid >> 6, lane = tid & 63;
  int quad = lane >> 4, l15 = lane & 15;
  f32x4 acc[2][4];
#pragma unroll
  for (int i = 0; i < 2; i++)
#pragma unroll
    for (int j = 0; j < 4; j++) acc[i][j] = (f32x4){0.f, 0.f, 0.f, 0.f};

  int xr = tid >> 1, xc = (tid & 1) * 32;
  int wn = tid >> 2, wk = (tid & 3) * 16;
  const u16* Ap0 = A + (size_t)(arow0 + xr) * K + xc;
  bool wvalid = (n0 + wn) < N;
  const u16* Wp0 = WT + (size_t)(wvalid ? (n0 + wn) : 0) * K + wk;

  for (int k0 = 0; k0 < K; k0 += 64) {
    bf16x8 xv[4];
#pragma unroll
    for (int i = 0; i < 4; i++) xv[i] = *(const bf16x8*)(Ap0 + k0 + 8 * i);
    bf16x8 wv[2];
#pragma unroll
    for (int i = 0; i < 2; i++)
      wv[i] = wvalid ? *(const bf16x8*)(Wp0 + k0 + 8 * i)
                     : (bf16x8){0,0,0,0,0,0,0,0};
    __syncthreads();
#pragma unroll
    for (int i = 0; i < 4; i++)
      *(bf16x8*)&Xs[xr * XS_S + xc + 8 * i] = xv[i];
#pragma unroll
    for (int i = 0; i < 2; i++)
      *(bf16x8*)&Wt[wn * WT_S + wk + 8 * i] = wv[i];
    __syncthreads();
#pragma unroll
    for (int kh = 0; kh < 2; kh++) {
      int kk = kh * 32 + quad * 8;
      bf16x8 a0 = *(const bf16x8*)&Xs[(w * 32 + l15) * XS_S + kk];
      bf16x8 a1 = *(const bf16x8*)&Xs[(w * 32 + 16 + l15) * XS_S + kk];
#pragma unroll
      for (int nt = 0; nt < 4; nt++) {
        bf16x8 b = *(const bf16x8*)&Wt[(nt * 16 + l15) * WT_S + kk];
        acc[0][nt] = __builtin_amdgcn_mfma_f32_16x16x32_bf16(a0, b, acc[0][nt], 0, 0, 0);
        acc[1][nt] = __builtin_amdgcn_mfma_f32_16x16x32_bf16(a1, b, acc[1][nt], 0, 0, 0);
      }
    }
  }

#pragma unroll
  for (int sub = 0; sub < 2; sub++)
#pragma unroll
    for (int nt = 0; nt < 4; nt++)
#pragma unroll
      for (int r = 0; r < 4; r++) {
        int m = w * 32 + sub * 16 + quad * 4 + r;
        int n = n0 + nt * 16 + l15;
        if (n < N) {
          float v = acc[sub][nt][r];
          if (BIAS)  v += b2f(bias[n]);
          if (RESID) v += b2f(resid[(size_t)(crow0 + m) * ldC + n]);
          if (RELU)  v = fmaxf(v, 0.f);
          if (OUTF32) ((float*)Cout)[(size_t)(crow0 + m) * ldC + n] = v;
          else        ((bf16*)Cout)[(size_t)(crow0 + m) * ldC + n]  = f2b(v);
        }
      }
}

#define MGEMM_LDS __shared__ s16 Xs[128 * XS_S]; __shared__ s16 Wt[64 * WT_S];

// proj (64-wide): swizzled 1D grid (6 * mtiles).
__global__ __launch_bounds__(256) void proj_mfma(
    const bf16* A, const bf16* Wbuf, bf16* x, int tok0, int mtiles)
{
  MGEMM_LDS
  int nt, mblk;
  swz(blockIdx.x, 6, mtiles, nt, mblk);
  int n0 = nt * 64, m0 = mblk * 128;
  mgemm_core<0,1,0,1>(Xs, Wt, (const u16*)A,
                      (const u16*)Wbuf + OFF_PROJ, (const bf16*)Wbuf + OFF_BPROJ,
                      x, x, D_, D_, D_, m0, tok0 + m0, n0);
}

// ffn2 (64-wide): swizzled 1D grid (6 * mtiles). K=1536.
__global__ __launch_bounds__(256) void ffn2_mfma(
    const bf16* midc, const bf16* Wbuf, bf16* x, int tok0, int mtiles)
{
  MGEMM_LDS
  int nt, mblk;
  swz(blockIdx.x, 6, mtiles, nt, mblk);
  int n0 = nt * 64, m0 = mblk * 128;
  mgemm_core<0,1,0,1>(Xs, Wt, (const u16*)midc,
                      (const u16*)Wbuf + OFF_W2T, (const bf16*)Wbuf + OFF_B2,
                      x, x, D_, D_, 4 * D_, m0, tok0 + m0, n0);
}

// head (64-wide): plain A = hc (chunk-local), f32 out rows tok0+m.
__global__ __launch_bounds__(256) void head_mfma(
    const bf16* hc, const bf16* Hbuf, float* out, int tok0)
{
  MGEMM_LDS
  int n0 = blockIdx.x * 64, m0 = blockIdx.y * 128;
  mgemm_core<0,0,1,1>(Xs, Wt, (const u16*)hc,
                      (const u16*)Hbuf + HOFF_WHT, (const bf16*)Hbuf + HOFF_BH,
                      nullptr, out, V_, V_, D_, m0, tok0 + m0, n0);
}

// ---------------------------------------------------------------------------
// mg128: 128m x 128n x 64k MFMA core (R14-verified), plain A.
// ---------------------------------------------------------------------------
template<class Epi>
__device__ __forceinline__ void mg128(
    s16* __restrict__ Xs, s16* __restrict__ Ws,
    const u16* __restrict__ A,
    const u16* __restrict__ WT, int N, int K, int arow0, int n0, Epi epi)
{
  int tid = threadIdx.x;
  int w = tid >> 6, lane = tid & 63;
  int quad = lane >> 4, l15 = lane & 15;
  int wm = (w >> 1) * 64, wn = (w & 1) * 64;
  f32x4 acc[4][4];
#pragma unroll
  for (int i = 0; i < 4; i++)
#pragma unroll
    for (int j = 0; j < 4; j++) acc[i][j] = (f32x4){0.f, 0.f, 0.f, 0.f};

  int sr = tid >> 1, sc = (tid & 1) * 32;
  const u16* Ap0 = A + (size_t)(arow0 + sr) * K + sc;
  bool nv = (n0 + sr) < N;
  const u16* Wp0 = WT + (size_t)(nv ? (n0 + sr) : 0) * K + sc;

  for (int k0 = 0; k0 < K; k0 += 64) {
    bf16x8 xv[4], wv[4];
#pragma unroll
    for (int i = 0; i < 4; i++) xv[i] = *(const bf16x8*)(Ap0 + k0 + 8 * i);
#pragma unroll
    for (int i = 0; i < 4; i++)
      wv[i] = nv ? *(const bf16x8*)(Wp0 + k0 + 8 * i)
                 : (bf16x8){0,0,0,0,0,0,0,0};
    __syncthreads();
#pragma unroll
    for (int i = 0; i < 4; i++) {
      *(bf16x8*)&Xs[sr * 72 + sc + 8 * i] = xv[i];
      *(bf16x8*)&Ws[sr * 72 + sc + 8 * i] = wv[i];
    }
    __syncthreads();
#pragma unroll
    for (int kh = 0; kh < 2; kh++) {
      int kk = kh * 32 + quad * 8;
      bf16x8 am[4], bn[4];
#pragma unroll
      for (int i = 0; i < 4; i++)
        am[i] = *(const bf16x8*)&Xs[(wm + i * 16 + l15) * 72 + kk];
#pragma unroll
      for (int j = 0; j < 4; j++)
        bn[j] = *(const bf16x8*)&Ws[(wn + j * 16 + l15) * 72 + kk];
#pragma unroll
      for (int i = 0; i < 4; i++)
#pragma unroll
        for (int j = 0; j < 4; j++)
          acc[i][j] = __builtin_amdgcn_mfma_f32_16x16x32_bf16(am[i], bn[j], acc[i][j], 0, 0, 0);
    }
  }

#pragma unroll
  for (int i = 0; i < 4; i++)
#pragma unroll
    for (int j = 0; j < 4; j++)
#pragma unroll
      for (int r = 0; r < 4; r++) {
        int m = wm + i * 16 + quad * 4 + r;
        int n = n0 + wn + j * 16 + l15;
        if (n < N) epi(m, n, acc[i][j][r]);
      }
}

#define MG128_LDS __shared__ s16 Xs[128 * 72]; __shared__ s16 Ws[128 * 72];

// QKV N=1152 (R14-verified scatter). Swizzled 1D grid (9 * mtiles).
__global__ __launch_bounds__(256) void qkv128(
    const bf16* hc, const bf16* Wbuf, bf16* qkvc, int MCa, int mtiles)
{
  MG128_LDS
  int nt, mblk;
  swz(blockIdx.x, 9, mtiles, nt, mblk);
  int n0 = nt * 128, mloc0 = mblk * 128;
  auto epi = [&](int m, int n, float v) {
    int mat = n / 384;
    int rem = n - mat * 384;
    int hh = rem >> 6, hd = rem & 63;
    qkvc[(size_t)mat * MCa * D_ + (size_t)hh * MCa * HD_
         + (size_t)(mloc0 + m) * HD_ + hd] = f2b(v);
  };
  mg128(Xs, Ws, (const u16*)hc,
        (const u16*)Wbuf + OFF_QKV, 1152, D_, mloc0, n0, epi);
}

// ffn1 (128-wide): ReLU -> midc. Swizzled 1D grid (12 * mtiles).
__global__ __launch_bounds__(256) void ffn1_128(
    const bf16* hc, const bf16* Wbuf, bf16* midc, int mtiles)
{
  MG128_LDS
  int nt, mblk;
  swz(blockIdx.x, 12, mtiles, nt, mblk);
  int n0 = nt * 128, m0 = mblk * 128;
  const bf16* bias = (const bf16*)Wbuf + OFF_B1;
  auto epi = [&](int m, int n, float v) {
    float r = v + b2f(bias[n]);
    midc[(size_t)(m0 + m) * (4 * D_) + n] = f2b(fmaxf(r, 0.f));
  };
  mg128(Xs, Ws, (const u16*)hc,
        (const u16*)Wbuf + OFF_W1T, 4 * D_, D_, m0, n0, epi);
}

// ---------------------------------------------------------------------------
// MFMA flash attention with online softmax (R13-proven).
// ---------------------------------------------------------------------------
__global__ __launch_bounds__(256) void attn4_kernel(
    const bf16* __restrict__ Q, const bf16* __restrict__ K,
    const bf16* __restrict__ V, bf16* __restrict__ att, int MCa)
{
  __shared__ s16 Qs[64 * 72];
  __shared__ s16 Ks[64 * 72];
  __shared__ s16 Vs[64 * 73];
  __shared__ s16 Ps[4][16 * 72];
  const float scale = 0.05103103630798288f;   // 384^-0.5 (full-D scaling!)
  int tid = threadIdx.x;
  int w = tid >> 6, lane = tid & 63;
  int quad = lane >> 4, l15 = lane & 15;
  int bid = blockIdx.x;
  int qt = bid & 3;
  int bh = bid >> 2;
  int b = bh / H_, h = bh - b * H_;
  size_t base = ((size_t)h * MCa + (size_t)b * T_) * HD_;
  int q0 = qt * 64;
  int cq = qt;

#pragma unroll
  for (int i = 0; i < 2; i++) {
    int e = i * 256 + tid;
    int r = e >> 3, c = (e & 7) * 8;
    *(bf16x8*)&Qs[r * 72 + c] =
        *(const bf16x8*)((const u16*)Q + base + (size_t)(q0 + r) * HD_ + c);
  }

  float mrow[4] = {-1e30f, -1e30f, -1e30f, -1e30f};
  float lrow[4] = {0.f, 0.f, 0.f, 0.f};
  f32x4 O[4];
#pragma unroll
  for (int nt = 0; nt < 4; nt++) O[nt] = (f32x4){0.f, 0.f, 0.f, 0.f};

  for (int c = 0; c <= cq; c++) {
    __syncthreads();
#pragma unroll
    for (int i = 0; i < 2; i++) {
      int e = i * 256 + tid;
      int r = e >> 3, cc = (e & 7) * 8;
      *(bf16x8*)&Ks[r * 72 + cc] =
          *(const bf16x8*)((const u16*)K + base + (size_t)(c * 64 + r) * HD_ + cc);
      bf16x8 vv =
          *(const bf16x8*)((const u16*)V + base + (size_t)(c * 64 + r) * HD_ + cc);
#pragma unroll
      for (int k = 0; k < 8; k++) Vs[r * 73 + cc + k] = vv[k];
    }
    __syncthreads();

    f32x4 S[4];
#pragma unroll
    for (int nt = 0; nt < 4; nt++) S[nt] = (f32x4){0.f, 0.f, 0.f, 0.f};
#pragma unroll
    for (int ks = 0; ks < 2; ks++) {
      int kk = ks * 32 + quad * 8;
      bf16x8 a = *(const bf16x8*)&Qs[(w * 16 + l15) * 72 + kk];
#pragma unroll
      for (int nt = 0; nt < 4; nt++) {
        bf16x8 bb8 = *(const bf16x8*)&Ks[(nt * 16 + l15) * 72 + kk];
        S[nt] = __builtin_amdgcn_mfma_f32_16x16x32_bf16(a, bb8, S[nt], 0, 0, 0);
      }
    }

#pragma unroll
    for (int nt = 0; nt < 4; nt++)
#pragma unroll
      for (int r = 0; r < 4; r++) {
        int qrow = q0 + w * 16 + quad * 4 + r;
        int sg = c * 64 + nt * 16 + l15;
        float v = S[nt][r] * scale;
        S[nt][r] = (sg <= qrow) ? v : -1e30f;
      }

    float alpha[4];
#pragma unroll
    for (int r = 0; r < 4; r++) {
      float mc = fmaxf(fmaxf(S[0][r], S[1][r]), fmaxf(S[2][r], S[3][r]));
#pragma unroll
      for (int o = 1; o < 16; o <<= 1) mc = fmaxf(mc, __shfl_xor(mc, o, 64));
      float mn = fmaxf(mrow[r], mc);
      alpha[r] = __expf(mrow[r] - mn);
      mrow[r] = mn;
      float s = 0.f;
#pragma unroll
      for (int nt = 0; nt < 4; nt++) {
        float p = __expf(S[nt][r] - mn);
        S[nt][r] = p;
        s += p;
      }
#pragma unroll
      for (int o = 1; o < 16; o <<= 1) s += __shfl_xor(s, o, 64);
      lrow[r] = lrow[r] * alpha[r] + s;
    }
#pragma unroll
    for (int nt = 0; nt < 4; nt++)
#pragma unroll
      for (int r = 0; r < 4; r++) O[nt][r] *= alpha[r];

#pragma unroll
    for (int nt = 0; nt < 4; nt++)
#pragma unroll
      for (int r = 0; r < 4; r++)
        Ps[w][(quad * 4 + r) * 72 + nt * 16 + l15] = (s16)f2u(S[nt][r]);
    __syncthreads();
#pragma unroll
    for (int ks = 0; ks < 2; ks++) {
      bf16x8 a = *(const bf16x8*)&Ps[w][l15 * 72 + ks * 32 + quad * 8];
#pragma unroll
      for (int nt = 0; nt < 4; nt++) {
        bf16x8 bb8;
#pragma unroll
        for (int j = 0; j < 8; j++)
          bb8[j] = Vs[(ks * 32 + quad * 8 + j) * 73 + nt * 16 + l15];
        O[nt] = __builtin_amdgcn_mfma_f32_16x16x32_bf16(a, bb8, O[nt], 0, 0, 0);
      }
    }
  }

#pragma unroll
  for (int r = 0; r < 4; r++) {
    float invl = 1.0f / lrow[r];
#pragma unroll
    for (int nt = 0; nt < 4; nt++) {
      int qrow = q0 + w * 16 + quad * 4 + r;
      att[(size_t)(b * T_ + qrow) * D_ + h * HD_ + nt * 16 + l15] =
          f2b(O[nt][r] * invl);
    }
  }
}

// ---------------------------------------------------------------------------
extern "C" void kernel_launch(void* const* d_in, const int* in_sizes, int n_in,
                              void* d_out, int out_size, void* d_ws, size_t ws_size,
                              hipStream_t stream)
{
  float* out = (float*)d_out;
  dim3 blk(256);
  int outg = (out_size + 255) / 256;

  static const int expected[20] = {
      16384, 24960, 98304, 884736, 884736, 884736, 884736, 2304,
      3538944, 9216, 3538944, 2304, 2304, 2304, 2304, 2304, 384, 384,
      24960, 65};
  if (n_in != 20) { const_kernel<<<outg, blk, 0, stream>>>(out, out_size, 5.0f); return; }
  for (int i = 0; i < 20; i++)
    if (in_sizes[i] != expected[i]) {
      const_kernel<<<outg, blk, 0, stream>>>(out, out_size, 10.0f * (i + 1));
      return;
    }
  if (out_size != BT * V_) { const_kernel<<<outg, blk, 0, stream>>>(out, out_size, 7.0f); return; }

  const void* idx   = d_in[0];
  const void* tok   = d_in[1];
  const void* pos   = d_in[2];
  const void* Wq    = d_in[3];
  const void* Wk    = d_in[4];
  const void* Wv    = d_in[5];
  const void* Wproj = d_in[6];
  const void* bproj = d_in[7];
  const void* W1    = d_in[8];
  const void* b1    = d_in[9];
  const void* W2    = d_in[10];
  const void* b2    = d_in[11];
  const void* ln1g  = d_in[12];
  const void* ln1b  = d_in[13];
  const void* ln2g  = d_in[14];
  const void* ln2b  = d_in[15];
  const void* lnfg  = d_in[16];
  const void* lnfb  = d_in[17];
  const void* Whead = d_in[18];
  const void* bhead = d_in[19];

  const size_t off_x  = 256;
  const size_t off_wb = off_x + (size_t)BT * D_ * 2;
  const size_t off_hb = off_wb + (size_t)WBUF_E * 2;
  const size_t fixed  = off_hb + ((size_t)HBUF_E * 2 + 63) / 64 * 64;
  if (ws_size < fixed) {
    const_kernel<<<outg, blk, 0, stream>>>(out, out_size, 0.0f);
    return;
  }
  size_t region = ws_size - fixed;

  // Chunk region = 5 units of MCc*D bf16 (attn: hc|qkv3|att; ffn: hc|mid4).
  int nc = 0;
  const int candn[7] = {1, 2, 4, 8, 16, 32, 64};
  for (int i = 0; i < 7; i++)
    if ((size_t)5 * (BT / candn[i]) * D_ * 2 <= region) { nc = candn[i]; break; }
  if (!nc) { const_kernel<<<outg, blk, 0, stream>>>(out, out_size, 0.0f); return; }
  const int MCc = BT / nc;
  const int CBc = MCc / T_;     // sequences per chunk
  const int mtiles = MCc / 128;

  char* wsb = (char*)d_ws;
  unsigned* flags = (unsigned*)wsb;
  bf16*   x    = (bf16*)(wsb + off_x);
  bf16*   Wbuf = (bf16*)(wsb + off_wb);
  bf16*   Hbuf = (bf16*)(wsb + off_hb);
  bf16*   hc   = (bf16*)(wsb + fixed);
  bf16*   qkvc = hc + (size_t)MCc * D_;
  bf16*   attc = qkvc + (size_t)3 * MCc * D_;
  bf16*   midc = qkvc;                          // overlays qkv+att

  detect_kernel<<<dim3(20), blk, 0, stream>>>(
      tok, pos, Wq, Wk, Wv, Wproj, bproj, W1, b1, W2, b2,
      ln1g, ln1b, ln2g, ln2b, lnfg, lnfb, Whead, bhead,
      (const int*)idx, flags);
  embed_kernel<<<dim3(BT * D_ / 256), blk, 0, stream>>>(idx, tok, pos, x, flags);
  conv_head<<<dim3((HBUF_E + 255) / 256), blk, 0, stream>>>(
      Whead, bhead, lnfg, lnfb, flags, Hbuf);

  for (int l = 0; l < L_; l++) {
    conv_layer<<<dim3((WBUF_E + 255) / 256), blk, 0, stream>>>(
        Wq, Wk, Wv, Wproj, bproj, W1, b1, W2, b2,
        ln1g, ln1b, ln2g, ln2b, flags, Wbuf, l);
    for (int c = 0; c < nc; c++) {
      int tok0 = c * MCc;
      lnw_kernel<<<dim3(MCc / 4), blk, 0, stream>>>(
          x, (const u16*)Wbuf + OFF_LN1G, (const u16*)Wbuf + OFF_LN1B, hc, tok0);
      qkv128<<<dim3(9 * mtiles), blk, 0, stream>>>(hc, Wbuf, qkvc, MCc, mtiles);
      attn4_kernel<<<dim3(CBc * H_ * 4), blk, 0, stream>>>(
          qkvc, qkvc + (size_t)MCc * D_, qkvc + (size_t)2 * MCc * D_, attc, MCc);
      proj_mfma<<<dim3(6 * mtiles), blk, 0, stream>>>(attc, Wbuf, x, tok0, mtiles);
    }
    for (int f = 0; f < nc; f++) {
      int tok0 = f * MCc;
      lnw_kernel<<<dim3(MCc / 4), blk, 0, stream>>>(
          x, (const u16*)Wbuf + OFF_LN2G, (const u16*)Wbuf + OFF_LN2B, hc, tok0);
      ffn1_128<<<dim3(12 * mtiles), blk, 0, stream>>>(hc, Wbuf, midc, mtiles);
      ffn2_mfma<<<dim3(6 * mtiles), blk, 0, stream>>>(midc, Wbuf, x, tok0, mtiles);
    }
  }

  for (int c = 0; c < nc; c++) {
    int tok0 = c * MCc;
    lnw_kernel<<<dim3(MCc / 4), blk, 0, stream>>>(
        x, (const u16*)Hbuf + HOFF_LNFG, (const u16*)Hbuf + HOFF_LNFB, hc, tok0);
    head_mfma<<<dim3(2, MCc / 128), blk, 0, stream>>>(hc, Hbuf, out, tok0);
  }
}